// Round 1
// baseline (949.675 us; speedup 1.0000x reference)
//
#include <hip/hip_runtime.h>
#include <hip/hip_bf16.h>

typedef unsigned short u16;
typedef short bf16x8 __attribute__((ext_vector_type(8)));
typedef float f32x4 __attribute__((ext_vector_type(4)));

#define N_TOK 8192
#define DIM   1024
#define HID   2048
#define ADIM  128
#define SEQ   2048

__device__ __forceinline__ u16 f2bf_bits(float f){
  unsigned u = __float_as_uint(f);
  unsigned r = (u + 0x7fffu + ((u >> 16) & 1u)) >> 16;
  return (u16)r;
}
__device__ __forceinline__ float siluf(float x){ return x / (1.f + __expf(-x)); }

__device__ __forceinline__ void gload16(const void* g, void* l){
  __builtin_amdgcn_global_load_lds((const __attribute__((address_space(1))) void*)g,
                                   (__attribute__((address_space(3))) void*)l, 16, 0, 0);
}

// ---------------- generic C = A @ B^T GEMM, 128x128 tile, BK=32 -------------
enum { EPI_BF16 = 0, EPI_F32 = 1, EPI_SILU = 2, EPI_P1 = 3, EPI_OUTSCALE = 4, EPI_OUTADD = 5 };

template<int EPI>
__global__ void __launch_bounds__(256, 2)
gemm_bt(const u16* __restrict__ Ag, const u16* __restrict__ Bg, int K,
        long sAz, long sBz, long sOz, long sRz,
        float* __restrict__ fout, u16* __restrict__ bout,
        const float* __restrict__ rowscale, int ldo, int col0, float alpha)
{
  __shared__ u16 lA[128 * 32];
  __shared__ u16 lB[128 * 32];
  const int tid = threadIdx.x, wave = tid >> 6, lane = tid & 63;
  const long brow = (long)blockIdx.y * 128, bcol = (long)blockIdx.x * 128;
  const u16* A = Ag + (long)blockIdx.z * sAz + brow * K;
  const u16* B = Bg + (long)blockIdx.z * sBz + bcol * K;
  const int wr = (wave >> 1) * 64, wc = (wave & 1) * 64;

  f32x4 acc[4][4];
  #pragma unroll
  for (int m = 0; m < 4; m++)
    #pragma unroll
    for (int n = 0; n < 4; n++)
      #pragma unroll
      for (int i = 0; i < 4; i++) acc[m][n][i] = 0.f;

  const int sr = tid >> 2, sk = (tid & 3) * 8;
  const u16* gA = A + (long)sr * K + sk;
  const u16* gB = B + (long)sr * K + sk;
  const long rstep = (long)64 * K;
  u16* lA0 = &lA[wave * 512]; u16* lA1 = &lA[2048 + wave * 512];
  u16* lB0 = &lB[wave * 512]; u16* lB1 = &lB[2048 + wave * 512];
  const int frow = lane & 15, fk = (lane >> 4) * 8;

  for (int kt = 0; kt < K; kt += 32) {
    gload16(gA, lA0); gload16(gA + rstep, lA1);
    gload16(gB, lB0); gload16(gB + rstep, lB1);
    gA += 32; gB += 32;
    asm volatile("s_waitcnt vmcnt(0)" ::: "memory");
    __syncthreads();
    bf16x8 af[4], bfv[4];
    #pragma unroll
    for (int m = 0; m < 4; m++) af[m] = *(const bf16x8*)&lA[(wr + m * 16 + frow) * 32 + fk];
    #pragma unroll
    for (int n = 0; n < 4; n++) bfv[n] = *(const bf16x8*)&lB[(wc + n * 16 + frow) * 32 + fk];
    #pragma unroll
    for (int m = 0; m < 4; m++)
      #pragma unroll
      for (int n = 0; n < 4; n++)
        acc[m][n] = __builtin_amdgcn_mfma_f32_16x16x32_bf16(af[m], bfv[n], acc[m][n], 0, 0, 0);
    __syncthreads();
  }

  const long r0 = brow + wr + ((lane >> 4) << 2);
  const long c0 = bcol + wc + (lane & 15);
  #pragma unroll
  for (int m = 0; m < 4; m++) {
    #pragma unroll
    for (int i = 0; i < 4; i++) {
      long r = r0 + m * 16 + i;
      #pragma unroll
      for (int n = 0; n < 4; n++) {
        long c = c0 + n * 16;
        float v = acc[m][n][i];
        if constexpr (EPI == EPI_BF16) {
          bout[r * ldo + col0 + c] = f2bf_bits(v);
        } else if constexpr (EPI == EPI_F32) {
          fout[r * ldo + c] = v;
        } else if constexpr (EPI == EPI_SILU) {
          v = fminf(5.f, fmaxf(-5.f, v));
          (bout + (long)blockIdx.z * sOz)[r * ldo + c] = f2bf_bits(siluf(v));
        } else if constexpr (EPI == EPI_P1) {
          float rs = (rowscale + (long)blockIdx.z * sRz)[r];
          (bout + (long)blockIdx.z * sOz)[r * ldo + col0 + c] = f2bf_bits(alpha * rs * v);
        } else if constexpr (EPI == EPI_OUTSCALE) {
          fout[r * ldo + c] = rowscale[r] * v;
        } else if constexpr (EPI == EPI_OUTADD) {
          fout[r * ldo + c] += v;
        }
      }
    }
  }
}

// -------- fused hidden = silu(x@Wg^T) * (x@Wu^T), 128x64 tile ---------------
__global__ void __launch_bounds__(256, 2)
gemm_dual(const u16* __restrict__ Ag, const u16* __restrict__ Gg,
          const u16* __restrict__ Ug, int K, int ldh, u16* __restrict__ hout)
{
  __shared__ u16 lA[128 * 32];
  __shared__ u16 lG[64 * 32];
  __shared__ u16 lU[64 * 32];
  const int tid = threadIdx.x, wave = tid >> 6, lane = tid & 63;
  const long brow = (long)blockIdx.y * 128, bcol = (long)blockIdx.x * 64;
  const u16* A = Ag + brow * K;
  const u16* G = Gg + bcol * K;
  const u16* U = Ug + bcol * K;
  const int wr = (wave >> 1) * 64, wc = (wave & 1) * 32;

  f32x4 ag[4][2], au[4][2];
  #pragma unroll
  for (int m = 0; m < 4; m++)
    #pragma unroll
    for (int n = 0; n < 2; n++)
      #pragma unroll
      for (int i = 0; i < 4; i++) { ag[m][n][i] = 0.f; au[m][n][i] = 0.f; }

  const int sr = tid >> 2, sk = (tid & 3) * 8;
  const u16* gA = A + (long)sr * K + sk;
  const u16* gG = G + (long)sr * K + sk;
  const u16* gU = U + (long)sr * K + sk;
  const long rstep = (long)64 * K;
  u16* lA0 = &lA[wave * 512]; u16* lA1 = &lA[2048 + wave * 512];
  u16* lG0 = &lG[wave * 512]; u16* lU0 = &lU[wave * 512];
  const int frow = lane & 15, fk = (lane >> 4) * 8;

  for (int kt = 0; kt < K; kt += 32) {
    gload16(gA, lA0); gload16(gA + rstep, lA1);
    gload16(gG, lG0); gload16(gU, lU0);
    gA += 32; gG += 32; gU += 32;
    asm volatile("s_waitcnt vmcnt(0)" ::: "memory");
    __syncthreads();
    bf16x8 af[4], bg[2], bu[2];
    #pragma unroll
    for (int m = 0; m < 4; m++) af[m] = *(const bf16x8*)&lA[(wr + m * 16 + frow) * 32 + fk];
    #pragma unroll
    for (int n = 0; n < 2; n++) bg[n] = *(const bf16x8*)&lG[(wc + n * 16 + frow) * 32 + fk];
    #pragma unroll
    for (int n = 0; n < 2; n++) bu[n] = *(const bf16x8*)&lU[(wc + n * 16 + frow) * 32 + fk];
    #pragma unroll
    for (int m = 0; m < 4; m++)
      #pragma unroll
      for (int n = 0; n < 2; n++) {
        ag[m][n] = __builtin_amdgcn_mfma_f32_16x16x32_bf16(af[m], bg[n], ag[m][n], 0, 0, 0);
        au[m][n] = __builtin_amdgcn_mfma_f32_16x16x32_bf16(af[m], bu[n], au[m][n], 0, 0, 0);
      }
    __syncthreads();
  }

  const long r0 = brow + wr + ((lane >> 4) << 2);
  const long c0 = bcol + wc + (lane & 15);
  #pragma unroll
  for (int m = 0; m < 4; m++)
    #pragma unroll
    for (int i = 0; i < 4; i++) {
      long r = r0 + m * 16 + i;
      #pragma unroll
      for (int n = 0; n < 2; n++) {
        long c = c0 + n * 16;
        hout[r * ldh + c] = f2bf_bits(siluf(ag[m][n][i]) * au[m][n][i]);
      }
    }
}

// ---------------- f32 -> bf16 conversions -----------------------------------
__global__ void cvt_bf16(const float* __restrict__ in, u16* __restrict__ out, int n)
{
  int i = (blockIdx.x * blockDim.x + threadIdx.x) * 8;
  if (i >= n) return;
  const float4* p = (const float4*)(in + i);
  float4 v0 = p[0], v1 = p[1];
  ushort4 a, b;
  a.x = f2bf_bits(v0.x); a.y = f2bf_bits(v0.y); a.z = f2bf_bits(v0.z); a.w = f2bf_bits(v0.w);
  b.x = f2bf_bits(v1.x); b.y = f2bf_bits(v1.y); b.z = f2bf_bits(v1.z); b.w = f2bf_bits(v1.w);
  *(ushort4*)(out + i) = a;
  *(ushort4*)(out + i + 4) = b;
}

// in [2048,128] -> out [128,2048] (bf16)
__global__ void cvt_t_bf16(const float* __restrict__ in, u16* __restrict__ out)
{
  int idx = blockIdx.x * 256 + threadIdx.x;      // 262144 total
  int c = idx >> 11, r = idx & 2047;
  out[idx] = f2bf_bits(in[(long)r * 128 + c]);
}

// ---------------- row LayerNorm over 128 cols -------------------------------
__global__ void __launch_bounds__(256)
ln_rows(const float* __restrict__ in, const float* __restrict__ g,
        const float* __restrict__ b, u16* __restrict__ out, u16* __restrict__ outT)
{
  int wave = threadIdx.x >> 6, lane = threadIdx.x & 63;
  long n = (long)blockIdx.x * 4 + wave;
  const float* row = in + n * 128;
  float x0 = row[lane], x1 = row[lane + 64];
  float s = x0 + x1, q = x0 * x0 + x1 * x1;
  #pragma unroll
  for (int o = 32; o; o >>= 1) { s += __shfl_xor(s, o); q += __shfl_xor(q, o); }
  float m = s * (1.f / 128.f);
  float var = q * (1.f / 128.f) - m * m;
  float inv = rsqrtf(var + 1e-5f);
  float y0 = (x0 - m) * inv * g[lane] + b[lane];
  float y1 = (x1 - m) * inv * g[lane + 64] + b[lane + 64];
  out[n * 128 + lane] = f2bf_bits(y0);
  out[n * 128 + 64 + lane] = f2bf_bits(y1);
  if (outT) {
    long bb = n >> 11, ss = n & 2047;
    outT[(bb * 128 + lane) * 2048 + ss] = f2bf_bits(y0);
    outT[(bb * 128 + lane + 64) * 2048 + ss] = f2bf_bits(y1);
  }
}

// ---------------- router (fp32 exact) ---------------------------------------
__global__ void __launch_bounds__(256)
router_kernel(const float* __restrict__ x, const float* __restrict__ Wrg,
              const float* __restrict__ Wre, float* __restrict__ sumw,
              float* __restrict__ fwv, int* __restrict__ eidxv,
              float* __restrict__ stats)
{
  int wave = threadIdx.x >> 6, lane = threadIdx.x & 63;
  long n = (long)blockIdx.x * 4 + wave;
  const float4* xr  = (const float4*)(x + n * 1024);
  const float4* wg0 = (const float4*)Wrg;
  const float4* wg1 = (const float4*)(Wrg + 1024);
  const float4* we0 = (const float4*)Wre;
  const float4* we1 = (const float4*)(Wre + 1024);
  const float4* we2 = (const float4*)(Wre + 2048);
  const float4* we3 = (const float4*)(Wre + 3072);
  float d0 = 0, d1 = 0, t0 = 0, t1 = 0, t2 = 0, t3 = 0;
  #pragma unroll
  for (int j = 0; j < 4; j++) {
    int id = j * 64 + lane;
    float4 xv = xr[id];
    float4 a;
    a = wg0[id]; d0 += xv.x * a.x + xv.y * a.y + xv.z * a.z + xv.w * a.w;
    a = wg1[id]; d1 += xv.x * a.x + xv.y * a.y + xv.z * a.z + xv.w * a.w;
    a = we0[id]; t0 += xv.x * a.x + xv.y * a.y + xv.z * a.z + xv.w * a.w;
    a = we1[id]; t1 += xv.x * a.x + xv.y * a.y + xv.z * a.z + xv.w * a.w;
    a = we2[id]; t2 += xv.x * a.x + xv.y * a.y + xv.z * a.z + xv.w * a.w;
    a = we3[id]; t3 += xv.x * a.x + xv.y * a.y + xv.z * a.z + xv.w * a.w;
  }
  #pragma unroll
  for (int o = 32; o; o >>= 1) {
    d0 += __shfl_xor(d0, o); d1 += __shfl_xor(d1, o);
    t0 += __shfl_xor(t0, o); t1 += __shfl_xor(t1, o);
    t2 += __shfl_xor(t2, o); t3 += __shfl_xor(t3, o);
  }
  if (lane == 0) {
    float mg = fmaxf(d0, d1);
    float e0 = __expf(d0 - mg), e1 = __expf(d1 - mg);
    float invg = 1.f / (e0 + e1);
    float p0 = e0 * invg, p1 = e1 * invg;
    int gi = (d1 > d0) ? 1 : 0;
    float gw = fmaxf(p0, p1);
    float l[4] = {t0, t1, t2, t3};
    float ml = fmaxf(fmaxf(l[0], l[1]), fmaxf(l[2], l[3]));
    float p[4]; float su = 0;
    #pragma unroll
    for (int i = 0; i < 4; i++) { p[i] = __expf(l[i] - ml); su += p[i]; }
    float isu = 1.f / su;
    #pragma unroll
    for (int i = 0; i < 4; i++) p[i] *= isu;
    int i1 = 0;
    #pragma unroll
    for (int i = 1; i < 4; i++) if (p[i] > p[i1]) i1 = i;
    int i2 = (i1 == 0) ? 1 : 0;
    #pragma unroll
    for (int i = 0; i < 4; i++) if (i != i1 && p[i] > p[i2]) i2 = i;
    float s2 = p[i1] + p[i2];
    float invs = 1.f / (s2 + 1e-7f);
    float f1 = gw * p[i1] * invs, f2 = gw * p[i2] * invs;
    int ea = gi * 4 + i1, eb = gi * 4 + i2;
    sumw[n] = f1 + f2;
    fwv[2 * n] = f1; fwv[2 * n + 1] = f2;
    eidxv[2 * n] = ea; eidxv[2 * n + 1] = eb;
    atomicAdd(&stats[ea], f1);
    atomicAdd(&stats[eb], f2);
    atomicAdd(&stats[8], d0 * d0 + d1 * d1);
    atomicAdd(&stats[9], t0 * t0 + t1 * t1 + t2 * t2 + t3 * t3);
  }
}

__global__ void init_stats(float* stats){ if (threadIdx.x < 16) stats[threadIdx.x] = 0.f; }

__global__ void finalize_loss(const float* __restrict__ stats, float* __restrict__ out)
{
  float tot = 0;
  #pragma unroll
  for (int e = 0; e < 8; e++) tot += stats[e];
  float target = tot * 0.125f;
  float lb = 0;
  #pragma unroll
  for (int e = 0; e < 8; e++) { float d = stats[e] - target; lb += d * d; }
  lb *= 0.125f;
  float z = stats[8] * (1.f / (8192.f * 2.f)) + stats[9] * (1.f / (8192.f * 4.f));
  out[0] = 0.001f * (lb + z);
}

// ------- expert path: wh = sum_k fw_k * LN(pre @ W_ead[e_k]^T); P[:,128:] ----
__global__ void __launch_bounds__(128)
expert_combine(const float* __restrict__ pre, const int* __restrict__ eidxv,
               const float* __restrict__ fwv, const float* __restrict__ W_ead,
               const float* __restrict__ g_e, const float* __restrict__ b_e,
               u16* __restrict__ P)
{
  __shared__ float sp[128];
  __shared__ float red[4];
  const int n = blockIdx.x, c = threadIdx.x;
  sp[c] = pre[(long)n * 128 + c];
  __syncthreads();
  float outv = 0.f;
  #pragma unroll
  for (int k = 0; k < 2; k++) {
    const int e = eidxv[2 * n + k];
    const float w = fwv[2 * n + k];
    const float* We = W_ead + ((long)e * 128 + c) * 128;
    float acc = 0.f;
    #pragma unroll 8
    for (int a = 0; a < 128; a++) acc += sp[a] * We[a];
    float s = acc, q = acc * acc;
    #pragma unroll
    for (int o = 32; o; o >>= 1) { s += __shfl_xor(s, o); q += __shfl_xor(q, o); }
    if ((c & 63) == 0) { red[(c >> 6) * 2] = s; red[(c >> 6) * 2 + 1] = q; }
    __syncthreads();
    float S2 = red[0] + red[2], Q2 = red[1] + red[3];
    __syncthreads();
    float m = S2 * (1.f / 128.f);
    float var = Q2 * (1.f / 128.f) - m * m;
    float inv = rsqrtf(var + 1e-5f);
    float he = (acc - m) * inv * g_e[e * 128 + c] + b_e[e * 128 + c];
    outv += w * he;
  }
  P[(long)n * 256 + 128 + c] = f2bf_bits(0.1f * outv);
}

// ----------------------------------------------------------------------------
extern "C" void kernel_launch(void* const* d_in, const int* in_sizes, int n_in,
                              void* d_out, int out_size, void* d_ws, size_t ws_size,
                              hipStream_t stream)
{
  (void)in_sizes; (void)n_in; (void)out_size; (void)ws_size;
  const float* x       = (const float*)d_in[0];
  const float* W_up    = (const float*)d_in[1];
  const float* W_gate  = (const float*)d_in[2];
  const float* W_down  = (const float*)d_in[3];
  const float* W_pre   = (const float*)d_in[4];
  const float* W_post  = (const float*)d_in[5];
  const float* g_an    = (const float*)d_in[6];
  const float* b_an    = (const float*)d_in[7];
  const float* W_aproj = (const float*)d_in[8];
  const float* W_ead   = (const float*)d_in[9];
  const float* g_e     = (const float*)d_in[10];
  const float* b_e     = (const float*)d_in[11];
  const float* W_eproj = (const float*)d_in[12];
  const float* W_oproj = (const float*)d_in[13];
  const float* W_rg    = (const float*)d_in[14];
  const float* W_re    = (const float*)d_in[15];
  float* out = (float*)d_out;

  char* base = (char*)d_ws; size_t off = 0;
  auto alloc = [&](size_t bytes) -> void* {
    void* p = base + off; off = (off + bytes + 255) & ~(size_t)255; return p;
  };
  u16*   xb     = (u16*)  alloc((size_t)N_TOK * DIM * 2);
  u16*   Wupb   = (u16*)  alloc((size_t)HID * DIM * 2);
  u16*   Wgb    = (u16*)  alloc((size_t)HID * DIM * 2);
  u16*   Wdb    = (u16*)  alloc((size_t)DIM * HID * 2);
  u16*   Wpostb = (u16*)  alloc((size_t)ADIM * HID * 2);
  u16*   Wpreb  = (u16*)  alloc((size_t)ADIM * DIM * 2);
  u16*   WaTb   = (u16*)  alloc((size_t)ADIM * HID * 2);
  u16*   WeTb   = (u16*)  alloc((size_t)ADIM * HID * 2);
  u16*   Wob    = (u16*)  alloc((size_t)DIM * HID * 2);
  u16*   Qb     = (u16*)  alloc((size_t)DIM * 256 * 2);
  u16*   hid    = (u16*)  alloc((size_t)N_TOK * HID * 2);
  float* pre    = (float*)alloc((size_t)N_TOK * ADIM * 4);
  float* postf  = (float*)alloc((size_t)N_TOK * ADIM * 4);
  u16*   a_in   = (u16*)  alloc((size_t)N_TOK * ADIM * 2);
  u16*   a_inT  = (u16*)  alloc((size_t)N_TOK * ADIM * 2);
  u16*   a_out  = (u16*)  alloc((size_t)N_TOK * ADIM * 2);
  u16*   Pb     = (u16*)  alloc((size_t)N_TOK * 256 * 2);
  float* sumw   = (float*)alloc((size_t)N_TOK * 4);
  float* fwv    = (float*)alloc((size_t)N_TOK * 2 * 4);
  int*   eidxv  = (int*)  alloc((size_t)N_TOK * 2 * 4);
  float* stats  = (float*)alloc(64);
  // aw (4 x 2048 x 2048 bf16, 33.5 MB) aliases d_out[0..8388607] — its lifetime
  // (scores GEMM -> adaptA GEMM) strictly precedes the down-GEMM's writes.
  u16* aw = (u16*)d_out;

  init_stats<<<1, 64, 0, stream>>>(stats);
  router_kernel<<<2048, 256, 0, stream>>>(x, W_rg, W_re, sumw, fwv, eidxv, stats);

  cvt_bf16<<<4096, 256, 0, stream>>>(x, xb, N_TOK * DIM);
  cvt_bf16<<<1024, 256, 0, stream>>>(W_up, Wupb, HID * DIM);
  cvt_bf16<<<1024, 256, 0, stream>>>(W_gate, Wgb, HID * DIM);
  cvt_bf16<<<1024, 256, 0, stream>>>(W_down, Wdb, DIM * HID);
  cvt_bf16<<<128, 256, 0, stream>>>(W_post, Wpostb, ADIM * HID);
  cvt_bf16<<<64, 256, 0, stream>>>(W_pre, Wpreb, ADIM * DIM);
  cvt_bf16<<<1024, 256, 0, stream>>>(W_oproj, Wob, DIM * HID);
  cvt_t_bf16<<<1024, 256, 0, stream>>>(W_aproj, WaTb);
  cvt_t_bf16<<<1024, 256, 0, stream>>>(W_eproj, WeTb);

  // M2 = W_down @ W_aproj -> Q[:,0:128];  M1 = W_oproj @ W_eproj -> Q[:,128:256]
  gemm_bt<EPI_BF16><<<dim3(1, 8, 1), 256, 0, stream>>>(Wdb, WaTb, HID, 0, 0, 0, 0,
      nullptr, Qb, nullptr, 256, 0, 0.f);
  gemm_bt<EPI_BF16><<<dim3(1, 8, 1), 256, 0, stream>>>(Wob, WeTb, HID, 0, 0, 0, 0,
      nullptr, Qb, nullptr, 256, 128, 0.f);

  // hidden = silu(x@Wg^T) * (x@Wu^T)   [N,H] bf16
  gemm_dual<<<dim3(32, 64, 1), 256, 0, stream>>>(xb, Wgb, Wupb, DIM, HID, hid);

  // pre = x @ W_pre^T  [N,128] f32 ; a_in = LN(pre) (+ transposed copy)
  gemm_bt<EPI_F32><<<dim3(1, 64, 1), 256, 0, stream>>>(xb, Wpreb, DIM, 0, 0, 0, 0,
      pre, nullptr, nullptr, ADIM, 0, 0.f);
  ln_rows<<<2048, 256, 0, stream>>>(pre, g_an, b_an, a_in, a_inT);

  // postf = hidden @ W_post^T ; a_out = LN(postf)
  gemm_bt<EPI_F32><<<dim3(1, 64, 1), 256, 0, stream>>>(hid, Wpostb, HID, 0, 0, 0, 0,
      postf, nullptr, nullptr, ADIM, 0, 0.f);
  ln_rows<<<2048, 256, 0, stream>>>(postf, g_an, b_an, a_out, nullptr);

  // aw[b] = silu(clip(a_in_b @ a_out_b^T))  (bf16, aliased onto d_out)
  gemm_bt<EPI_SILU><<<dim3(16, 16, 4), 256, 0, stream>>>(a_in, a_out, ADIM,
      (long)SEQ * ADIM, (long)SEQ * ADIM, (long)SEQ * SEQ, 0,
      nullptr, aw, nullptr, SEQ, 0, 0.f);

  // P[:, :128] = 0.1 * sumw * (aw_b @ a_in_b)   (K = SEQ)
  gemm_bt<EPI_P1><<<dim3(1, 16, 4), 256, 0, stream>>>(aw, a_inT, SEQ,
      (long)SEQ * SEQ, (long)ADIM * SEQ, (long)SEQ * 256, SEQ,
      nullptr, Pb, sumw, 256, 0, 0.1f);

  // P[:, 128:] = 0.1 * wh  (expert adapters, fp32)
  expert_combine<<<8192, 128, 0, stream>>>(pre, eidxv, fwv, W_ead, g_e, b_e, Pb);

  // out = sumw * (hidden @ W_down^T)
  gemm_bt<EPI_OUTSCALE><<<dim3(8, 64, 1), 256, 0, stream>>>(hid, Wdb, HID, 0, 0, 0, 0,
      out, nullptr, sumw, DIM, 0, 0.f);
  // out += P @ Q^T   (K = 256)
  gemm_bt<EPI_OUTADD><<<dim3(8, 64, 1), 256, 0, stream>>>(Pb, Qb, 256, 0, 0, 0, 0,
      out, nullptr, nullptr, DIM, 0, 0.f);

  finalize_loss<<<1, 1, 0, stream>>>(stats, out + (size_t)N_TOK * DIM);
}

// Round 2
// 530.092 us; speedup vs baseline: 1.7915x; 1.7915x over previous
//
#include <hip/hip_runtime.h>
#include <hip/hip_bf16.h>

typedef unsigned short u16;
typedef short bf16x8 __attribute__((ext_vector_type(8)));
typedef float f32x4 __attribute__((ext_vector_type(4)));

#define N_TOK 8192
#define DIM   1024
#define HID   2048
#define ADIM  128
#define SEQ   2048

__device__ __forceinline__ u16 f2bf_bits(float f){
  unsigned u = __float_as_uint(f);
  unsigned r = (u + 0x7fffu + ((u >> 16) & 1u)) >> 16;
  return (u16)r;
}
__device__ __forceinline__ float siluf(float x){ return x / (1.f + __expf(-x)); }

__device__ __forceinline__ void gload16(const void* g, void* l){
  __builtin_amdgcn_global_load_lds((const __attribute__((address_space(1))) void*)g,
                                   (__attribute__((address_space(3))) void*)l, 16, 0, 0);
}

// ---------------- generic C = A @ B^T GEMM, 128x128 tile, BK=32 -------------
enum { EPI_BF16 = 0, EPI_F32 = 1, EPI_SILU = 2, EPI_P1 = 3, EPI_OUTSCALE = 4, EPI_OUTADD = 5 };

template<int EPI>
__global__ void __launch_bounds__(256, 2)
gemm_bt(const u16* __restrict__ Ag, const u16* __restrict__ Bg, int K,
        long sAz, long sBz, long sOz, long sRz,
        float* __restrict__ fout, u16* __restrict__ bout,
        const float* __restrict__ rowscale, int ldo, int col0, float alpha)
{
  __shared__ u16 lA[128 * 32];
  __shared__ u16 lB[128 * 32];
  const int tid = threadIdx.x, wave = tid >> 6, lane = tid & 63;
  const long brow = (long)blockIdx.y * 128, bcol = (long)blockIdx.x * 128;
  const u16* A = Ag + (long)blockIdx.z * sAz + brow * K;
  const u16* B = Bg + (long)blockIdx.z * sBz + bcol * K;
  const int wr = (wave >> 1) * 64, wc = (wave & 1) * 64;

  f32x4 acc[4][4];
  #pragma unroll
  for (int m = 0; m < 4; m++)
    #pragma unroll
    for (int n = 0; n < 4; n++)
      #pragma unroll
      for (int i = 0; i < 4; i++) acc[m][n][i] = 0.f;

  const int sr = tid >> 2, sk = (tid & 3) * 8;
  const u16* gA = A + (long)sr * K + sk;
  const u16* gB = B + (long)sr * K + sk;
  const long rstep = (long)64 * K;
  u16* lA0 = &lA[wave * 512]; u16* lA1 = &lA[2048 + wave * 512];
  u16* lB0 = &lB[wave * 512]; u16* lB1 = &lB[2048 + wave * 512];
  const int frow = lane & 15, fk = (lane >> 4) * 8;

  for (int kt = 0; kt < K; kt += 32) {
    gload16(gA, lA0); gload16(gA + rstep, lA1);
    gload16(gB, lB0); gload16(gB + rstep, lB1);
    gA += 32; gB += 32;
    asm volatile("s_waitcnt vmcnt(0)" ::: "memory");
    __syncthreads();
    bf16x8 af[4], bfv[4];
    #pragma unroll
    for (int m = 0; m < 4; m++) af[m] = *(const bf16x8*)&lA[(wr + m * 16 + frow) * 32 + fk];
    #pragma unroll
    for (int n = 0; n < 4; n++) bfv[n] = *(const bf16x8*)&lB[(wc + n * 16 + frow) * 32 + fk];
    #pragma unroll
    for (int m = 0; m < 4; m++)
      #pragma unroll
      for (int n = 0; n < 4; n++)
        acc[m][n] = __builtin_amdgcn_mfma_f32_16x16x32_bf16(af[m], bfv[n], acc[m][n], 0, 0, 0);
    __syncthreads();
  }

  const long r0 = brow + wr + ((lane >> 4) << 2);
  const long c0 = bcol + wc + (lane & 15);
  #pragma unroll
  for (int m = 0; m < 4; m++) {
    #pragma unroll
    for (int i = 0; i < 4; i++) {
      long r = r0 + m * 16 + i;
      #pragma unroll
      for (int n = 0; n < 4; n++) {
        long c = c0 + n * 16;
        float v = acc[m][n][i];
        if constexpr (EPI == EPI_BF16) {
          bout[r * ldo + col0 + c] = f2bf_bits(v);
        } else if constexpr (EPI == EPI_F32) {
          fout[r * ldo + c] = v;
        } else if constexpr (EPI == EPI_SILU) {
          v = fminf(5.f, fmaxf(-5.f, v));
          (bout + (long)blockIdx.z * sOz)[r * ldo + c] = f2bf_bits(siluf(v));
        } else if constexpr (EPI == EPI_P1) {
          float rs = (rowscale + (long)blockIdx.z * sRz)[r];
          (bout + (long)blockIdx.z * sOz)[r * ldo + col0 + c] = f2bf_bits(alpha * rs * v);
        } else if constexpr (EPI == EPI_OUTSCALE) {
          fout[r * ldo + c] = rowscale[r] * v;
        } else if constexpr (EPI == EPI_OUTADD) {
          fout[r * ldo + c] += v;
        }
      }
    }
  }
}

// -------- fused hidden = silu(x@Wg^T) * (x@Wu^T), 128x64 tile ---------------
__global__ void __launch_bounds__(256, 2)
gemm_dual(const u16* __restrict__ Ag, const u16* __restrict__ Gg,
          const u16* __restrict__ Ug, int K, int ldh, u16* __restrict__ hout)
{
  __shared__ u16 lA[128 * 32];
  __shared__ u16 lG[64 * 32];
  __shared__ u16 lU[64 * 32];
  const int tid = threadIdx.x, wave = tid >> 6, lane = tid & 63;
  const long brow = (long)blockIdx.y * 128, bcol = (long)blockIdx.x * 64;
  const u16* A = Ag + brow * K;
  const u16* G = Gg + bcol * K;
  const u16* U = Ug + bcol * K;
  const int wr = (wave >> 1) * 64, wc = (wave & 1) * 32;

  f32x4 ag[4][2], au[4][2];
  #pragma unroll
  for (int m = 0; m < 4; m++)
    #pragma unroll
    for (int n = 0; n < 2; n++)
      #pragma unroll
      for (int i = 0; i < 4; i++) { ag[m][n][i] = 0.f; au[m][n][i] = 0.f; }

  const int sr = tid >> 2, sk = (tid & 3) * 8;
  const u16* gA = A + (long)sr * K + sk;
  const u16* gG = G + (long)sr * K + sk;
  const u16* gU = U + (long)sr * K + sk;
  const long rstep = (long)64 * K;
  u16* lA0 = &lA[wave * 512]; u16* lA1 = &lA[2048 + wave * 512];
  u16* lG0 = &lG[wave * 512]; u16* lU0 = &lU[wave * 512];
  const int frow = lane & 15, fk = (lane >> 4) * 8;

  for (int kt = 0; kt < K; kt += 32) {
    gload16(gA, lA0); gload16(gA + rstep, lA1);
    gload16(gG, lG0); gload16(gU, lU0);
    gA += 32; gG += 32; gU += 32;
    asm volatile("s_waitcnt vmcnt(0)" ::: "memory");
    __syncthreads();
    bf16x8 af[4], bg[2], bu[2];
    #pragma unroll
    for (int m = 0; m < 4; m++) af[m] = *(const bf16x8*)&lA[(wr + m * 16 + frow) * 32 + fk];
    #pragma unroll
    for (int n = 0; n < 2; n++) bg[n] = *(const bf16x8*)&lG[(wc + n * 16 + frow) * 32 + fk];
    #pragma unroll
    for (int n = 0; n < 2; n++) bu[n] = *(const bf16x8*)&lU[(wc + n * 16 + frow) * 32 + fk];
    #pragma unroll
    for (int m = 0; m < 4; m++)
      #pragma unroll
      for (int n = 0; n < 2; n++) {
        ag[m][n] = __builtin_amdgcn_mfma_f32_16x16x32_bf16(af[m], bg[n], ag[m][n], 0, 0, 0);
        au[m][n] = __builtin_amdgcn_mfma_f32_16x16x32_bf16(af[m], bu[n], au[m][n], 0, 0, 0);
      }
    __syncthreads();
  }

  const long r0 = brow + wr + ((lane >> 4) << 2);
  const long c0 = bcol + wc + (lane & 15);
  #pragma unroll
  for (int m = 0; m < 4; m++)
    #pragma unroll
    for (int i = 0; i < 4; i++) {
      long r = r0 + m * 16 + i;
      #pragma unroll
      for (int n = 0; n < 2; n++) {
        long c = c0 + n * 16;
        hout[r * ldh + c] = f2bf_bits(siluf(ag[m][n][i]) * au[m][n][i]);
      }
    }
}

// ---------------- f32 -> bf16 conversions -----------------------------------
__global__ void cvt_bf16(const float* __restrict__ in, u16* __restrict__ out, int n)
{
  int i = (blockIdx.x * blockDim.x + threadIdx.x) * 8;
  if (i >= n) return;
  const float4* p = (const float4*)(in + i);
  float4 v0 = p[0], v1 = p[1];
  ushort4 a, b;
  a.x = f2bf_bits(v0.x); a.y = f2bf_bits(v0.y); a.z = f2bf_bits(v0.z); a.w = f2bf_bits(v0.w);
  b.x = f2bf_bits(v1.x); b.y = f2bf_bits(v1.y); b.z = f2bf_bits(v1.z); b.w = f2bf_bits(v1.w);
  *(ushort4*)(out + i) = a;
  *(ushort4*)(out + i + 4) = b;
}

// in [2048,128] -> out [128,2048] (bf16)
__global__ void cvt_t_bf16(const float* __restrict__ in, u16* __restrict__ out)
{
  int idx = blockIdx.x * 256 + threadIdx.x;      // 262144 total
  int c = idx >> 11, r = idx & 2047;
  out[idx] = f2bf_bits(in[(long)r * 128 + c]);
}

// ---------------- row LayerNorm over 128 cols -------------------------------
__global__ void __launch_bounds__(256)
ln_rows(const float* __restrict__ in, const float* __restrict__ g,
        const float* __restrict__ b, u16* __restrict__ out, u16* __restrict__ outT)
{
  int wave = threadIdx.x >> 6, lane = threadIdx.x & 63;
  long n = (long)blockIdx.x * 4 + wave;
  const float* row = in + n * 128;
  float x0 = row[lane], x1 = row[lane + 64];
  float s = x0 + x1, q = x0 * x0 + x1 * x1;
  #pragma unroll
  for (int o = 32; o; o >>= 1) { s += __shfl_xor(s, o); q += __shfl_xor(q, o); }
  float m = s * (1.f / 128.f);
  float var = q * (1.f / 128.f) - m * m;
  float inv = rsqrtf(var + 1e-5f);
  float y0 = (x0 - m) * inv * g[lane] + b[lane];
  float y1 = (x1 - m) * inv * g[lane + 64] + b[lane + 64];
  out[n * 128 + lane] = f2bf_bits(y0);
  out[n * 128 + 64 + lane] = f2bf_bits(y1);
  if (outT) {
    long bb = n >> 11, ss = n & 2047;
    outT[(bb * 128 + lane) * 2048 + ss] = f2bf_bits(y0);
    outT[(bb * 128 + lane + 64) * 2048 + ss] = f2bf_bits(y1);
  }
}

// ---------------- router (fp32 exact, hierarchical stats reduction) ---------
// 512 blocks x 256 threads; wave handles 4 tokens; also emits x as bf16.
__global__ void __launch_bounds__(256)
router_kernel(const float* __restrict__ x, const float* __restrict__ Wrg,
              const float* __restrict__ Wre, float* __restrict__ sumw,
              float* __restrict__ fwv, int* __restrict__ eidxv,
              float* __restrict__ stats, u16* __restrict__ xb)
{
  __shared__ float lst[10];
  if (threadIdx.x < 10) lst[threadIdx.x] = 0.f;
  __syncthreads();
  const int wave = threadIdx.x >> 6, lane = threadIdx.x & 63;
  const float4* wg0 = (const float4*)Wrg;
  const float4* wg1 = (const float4*)(Wrg + 1024);
  const float4* we0 = (const float4*)Wre;
  const float4* we1 = (const float4*)(Wre + 1024);
  const float4* we2 = (const float4*)(Wre + 2048);
  const float4* we3 = (const float4*)(Wre + 3072);

  for (int t = 0; t < 4; t++) {
    const long n = (long)blockIdx.x * 16 + wave * 4 + t;
    const float4* xr = (const float4*)(x + n * 1024);
    float d0 = 0, d1 = 0, t0 = 0, t1 = 0, t2 = 0, t3 = 0;
    #pragma unroll
    for (int j = 0; j < 4; j++) {
      int id = j * 64 + lane;
      float4 xv = xr[id];
      ushort4 xc;
      xc.x = f2bf_bits(xv.x); xc.y = f2bf_bits(xv.y);
      xc.z = f2bf_bits(xv.z); xc.w = f2bf_bits(xv.w);
      *(ushort4*)(xb + n * 1024 + id * 4) = xc;
      float4 a;
      a = wg0[id]; d0 += xv.x * a.x + xv.y * a.y + xv.z * a.z + xv.w * a.w;
      a = wg1[id]; d1 += xv.x * a.x + xv.y * a.y + xv.z * a.z + xv.w * a.w;
      a = we0[id]; t0 += xv.x * a.x + xv.y * a.y + xv.z * a.z + xv.w * a.w;
      a = we1[id]; t1 += xv.x * a.x + xv.y * a.y + xv.z * a.z + xv.w * a.w;
      a = we2[id]; t2 += xv.x * a.x + xv.y * a.y + xv.z * a.z + xv.w * a.w;
      a = we3[id]; t3 += xv.x * a.x + xv.y * a.y + xv.z * a.z + xv.w * a.w;
    }
    #pragma unroll
    for (int o = 32; o; o >>= 1) {
      d0 += __shfl_xor(d0, o); d1 += __shfl_xor(d1, o);
      t0 += __shfl_xor(t0, o); t1 += __shfl_xor(t1, o);
      t2 += __shfl_xor(t2, o); t3 += __shfl_xor(t3, o);
    }
    if (lane == 0) {
      float mg = fmaxf(d0, d1);
      float e0 = __expf(d0 - mg), e1 = __expf(d1 - mg);
      float invg = 1.f / (e0 + e1);
      float p0 = e0 * invg, p1 = e1 * invg;
      int gi = (d1 > d0) ? 1 : 0;
      float gw = fmaxf(p0, p1);
      float l[4] = {t0, t1, t2, t3};
      float ml = fmaxf(fmaxf(l[0], l[1]), fmaxf(l[2], l[3]));
      float p[4]; float su = 0;
      #pragma unroll
      for (int i = 0; i < 4; i++) { p[i] = __expf(l[i] - ml); su += p[i]; }
      float isu = 1.f / su;
      #pragma unroll
      for (int i = 0; i < 4; i++) p[i] *= isu;
      int i1 = 0;
      #pragma unroll
      for (int i = 1; i < 4; i++) if (p[i] > p[i1]) i1 = i;
      int i2 = (i1 == 0) ? 1 : 0;
      #pragma unroll
      for (int i = 0; i < 4; i++) if (i != i1 && p[i] > p[i2]) i2 = i;
      float s2 = p[i1] + p[i2];
      float invs = 1.f / (s2 + 1e-7f);
      float f1 = gw * p[i1] * invs, f2 = gw * p[i2] * invs;
      int ea = gi * 4 + i1, eb = gi * 4 + i2;
      sumw[n] = f1 + f2;
      fwv[2 * n] = f1; fwv[2 * n + 1] = f2;
      eidxv[2 * n] = ea; eidxv[2 * n + 1] = eb;
      atomicAdd(&lst[ea], f1);
      atomicAdd(&lst[eb], f2);
      atomicAdd(&lst[8], d0 * d0 + d1 * d1);
      atomicAdd(&lst[9], t0 * t0 + t1 * t1 + t2 * t2 + t3 * t3);
    }
  }
  __syncthreads();
  if (threadIdx.x < 10) atomicAdd(&stats[threadIdx.x], lst[threadIdx.x]);
}

__global__ void init_stats(float* stats){ if (threadIdx.x < 16) stats[threadIdx.x] = 0.f; }

__global__ void finalize_loss(const float* __restrict__ stats, float* __restrict__ out)
{
  float tot = 0;
  #pragma unroll
  for (int e = 0; e < 8; e++) tot += stats[e];
  float target = tot * 0.125f;
  float lb = 0;
  #pragma unroll
  for (int e = 0; e < 8; e++) { float d = stats[e] - target; lb += d * d; }
  lb *= 0.125f;
  float z = stats[8] * (1.f / (8192.f * 2.f)) + stats[9] * (1.f / (8192.f * 4.f));
  out[0] = 0.001f * (lb + z);
}

// ------- expert path: wh = sum_k fw_k * LN(pre @ W_ead[e_k]^T); P[:,128:] ----
__global__ void __launch_bounds__(128)
expert_combine(const float* __restrict__ pre, const int* __restrict__ eidxv,
               const float* __restrict__ fwv, const float* __restrict__ W_ead,
               const float* __restrict__ g_e, const float* __restrict__ b_e,
               u16* __restrict__ P)
{
  __shared__ float sp[128];
  __shared__ float red[4];
  const int n = blockIdx.x, c = threadIdx.x;
  sp[c] = pre[(long)n * 128 + c];
  __syncthreads();
  float outv = 0.f;
  #pragma unroll
  for (int k = 0; k < 2; k++) {
    const int e = eidxv[2 * n + k];
    const float w = fwv[2 * n + k];
    const float* We = W_ead + ((long)e * 128 + c) * 128;
    float acc = 0.f;
    #pragma unroll 8
    for (int a = 0; a < 128; a++) acc += sp[a] * We[a];
    float s = acc, q = acc * acc;
    #pragma unroll
    for (int o = 32; o; o >>= 1) { s += __shfl_xor(s, o); q += __shfl_xor(q, o); }
    if ((c & 63) == 0) { red[(c >> 6) * 2] = s; red[(c >> 6) * 2 + 1] = q; }
    __syncthreads();
    float S2 = red[0] + red[2], Q2 = red[1] + red[3];
    __syncthreads();
    float m = S2 * (1.f / 128.f);
    float var = Q2 * (1.f / 128.f) - m * m;
    float inv = rsqrtf(var + 1e-5f);
    float he = (acc - m) * inv * g_e[e * 128 + c] + b_e[e * 128 + c];
    outv += w * he;
  }
  P[(long)n * 256 + 128 + c] = f2bf_bits(0.1f * outv);
}

// ----------------------------------------------------------------------------
extern "C" void kernel_launch(void* const* d_in, const int* in_sizes, int n_in,
                              void* d_out, int out_size, void* d_ws, size_t ws_size,
                              hipStream_t stream)
{
  (void)in_sizes; (void)n_in; (void)out_size; (void)ws_size;
  const float* x       = (const float*)d_in[0];
  const float* W_up    = (const float*)d_in[1];
  const float* W_gate  = (const float*)d_in[2];
  const float* W_down  = (const float*)d_in[3];
  const float* W_pre   = (const float*)d_in[4];
  const float* W_post  = (const float*)d_in[5];
  const float* g_an    = (const float*)d_in[6];
  const float* b_an    = (const float*)d_in[7];
  const float* W_aproj = (const float*)d_in[8];
  const float* W_ead   = (const float*)d_in[9];
  const float* g_e     = (const float*)d_in[10];
  const float* b_e     = (const float*)d_in[11];
  const float* W_eproj = (const float*)d_in[12];
  const float* W_oproj = (const float*)d_in[13];
  const float* W_rg    = (const float*)d_in[14];
  const float* W_re    = (const float*)d_in[15];
  float* out = (float*)d_out;

  char* base = (char*)d_ws; size_t off = 0;
  auto alloc = [&](size_t bytes) -> void* {
    void* p = base + off; off = (off + bytes + 255) & ~(size_t)255; return p;
  };
  u16*   xb     = (u16*)  alloc((size_t)N_TOK * DIM * 2);
  u16*   Wupb   = (u16*)  alloc((size_t)HID * DIM * 2);
  u16*   Wgb    = (u16*)  alloc((size_t)HID * DIM * 2);
  u16*   Wdb    = (u16*)  alloc((size_t)DIM * HID * 2);
  u16*   Wpostb = (u16*)  alloc((size_t)ADIM * HID * 2);
  u16*   Wpreb  = (u16*)  alloc((size_t)ADIM * DIM * 2);
  u16*   WaTb   = (u16*)  alloc((size_t)ADIM * HID * 2);
  u16*   WeTb   = (u16*)  alloc((size_t)ADIM * HID * 2);
  u16*   Wob    = (u16*)  alloc((size_t)DIM * HID * 2);
  u16*   Qb     = (u16*)  alloc((size_t)DIM * 256 * 2);
  u16*   hid    = (u16*)  alloc((size_t)N_TOK * HID * 2);
  float* pre    = (float*)alloc((size_t)N_TOK * ADIM * 4);
  float* postf  = (float*)alloc((size_t)N_TOK * ADIM * 4);
  u16*   a_in   = (u16*)  alloc((size_t)N_TOK * ADIM * 2);
  u16*   a_inT  = (u16*)  alloc((size_t)N_TOK * ADIM * 2);
  u16*   a_out  = (u16*)  alloc((size_t)N_TOK * ADIM * 2);
  u16*   Pb     = (u16*)  alloc((size_t)N_TOK * 256 * 2);
  float* sumw   = (float*)alloc((size_t)N_TOK * 4);
  float* fwv    = (float*)alloc((size_t)N_TOK * 2 * 4);
  int*   eidxv  = (int*)  alloc((size_t)N_TOK * 2 * 4);
  float* stats  = (float*)alloc(64);
  // aw (4 x 2048 x 2048 bf16, 33.5 MB) aliases d_out[0..8388607] — its lifetime
  // (scores GEMM -> adaptA GEMM) strictly precedes the down-GEMM's writes.
  u16* aw = (u16*)d_out;

  init_stats<<<1, 64, 0, stream>>>(stats);
  // router also produces xb (x as bf16)
  router_kernel<<<512, 256, 0, stream>>>(x, W_rg, W_re, sumw, fwv, eidxv, stats, xb);

  cvt_bf16<<<1024, 256, 0, stream>>>(W_up, Wupb, HID * DIM);
  cvt_bf16<<<1024, 256, 0, stream>>>(W_gate, Wgb, HID * DIM);
  cvt_bf16<<<1024, 256, 0, stream>>>(W_down, Wdb, DIM * HID);
  cvt_bf16<<<128, 256, 0, stream>>>(W_post, Wpostb, ADIM * HID);
  cvt_bf16<<<64, 256, 0, stream>>>(W_pre, Wpreb, ADIM * DIM);
  cvt_bf16<<<1024, 256, 0, stream>>>(W_oproj, Wob, DIM * HID);
  cvt_t_bf16<<<1024, 256, 0, stream>>>(W_aproj, WaTb);
  cvt_t_bf16<<<1024, 256, 0, stream>>>(W_eproj, WeTb);

  // M2 = W_down @ W_aproj -> Q[:,0:128];  M1 = W_oproj @ W_eproj -> Q[:,128:256]
  gemm_bt<EPI_BF16><<<dim3(1, 8, 1), 256, 0, stream>>>(Wdb, WaTb, HID, 0, 0, 0, 0,
      nullptr, Qb, nullptr, 256, 0, 0.f);
  gemm_bt<EPI_BF16><<<dim3(1, 8, 1), 256, 0, stream>>>(Wob, WeTb, HID, 0, 0, 0, 0,
      nullptr, Qb, nullptr, 256, 128, 0.f);

  // hidden = silu(x@Wg^T) * (x@Wu^T)   [N,H] bf16
  gemm_dual<<<dim3(32, 64, 1), 256, 0, stream>>>(xb, Wgb, Wupb, DIM, HID, hid);

  // pre = x @ W_pre^T  [N,128] f32 ; a_in = LN(pre) (+ transposed copy)
  gemm_bt<EPI_F32><<<dim3(1, 64, 1), 256, 0, stream>>>(xb, Wpreb, DIM, 0, 0, 0, 0,
      pre, nullptr, nullptr, ADIM, 0, 0.f);
  ln_rows<<<2048, 256, 0, stream>>>(pre, g_an, b_an, a_in, a_inT);

  // postf = hidden @ W_post^T ; a_out = LN(postf)
  gemm_bt<EPI_F32><<<dim3(1, 64, 1), 256, 0, stream>>>(hid, Wpostb, HID, 0, 0, 0, 0,
      postf, nullptr, nullptr, ADIM, 0, 0.f);
  ln_rows<<<2048, 256, 0, stream>>>(postf, g_an, b_an, a_out, nullptr);

  // aw[b] = silu(clip(a_in_b @ a_out_b^T))  (bf16, aliased onto d_out)
  gemm_bt<EPI_SILU><<<dim3(16, 16, 4), 256, 0, stream>>>(a_in, a_out, ADIM,
      (long)SEQ * ADIM, (long)SEQ * ADIM, (long)SEQ * SEQ, 0,
      nullptr, aw, nullptr, SEQ, 0, 0.f);

  // P[:, :128] = 0.1 * sumw * (aw_b @ a_in_b)   (K = SEQ)
  gemm_bt<EPI_P1><<<dim3(1, 16, 4), 256, 0, stream>>>(aw, a_inT, SEQ,
      (long)SEQ * SEQ, (long)ADIM * SEQ, (long)SEQ * 256, SEQ,
      nullptr, Pb, sumw, 256, 0, 0.1f);

  // P[:, 128:] = 0.1 * wh  (expert adapters, fp32)
  expert_combine<<<8192, 128, 0, stream>>>(pre, eidxv, fwv, W_ead, g_e, b_e, Pb);

  // out = sumw * (hidden @ W_down^T)
  gemm_bt<EPI_OUTSCALE><<<dim3(8, 64, 1), 256, 0, stream>>>(hid, Wdb, HID, 0, 0, 0, 0,
      out, nullptr, sumw, DIM, 0, 0.f);
  // out += P @ Q^T   (K = 256)
  gemm_bt<EPI_OUTADD><<<dim3(8, 64, 1), 256, 0, stream>>>(Pb, Qb, 256, 0, 0, 0, 0,
      out, nullptr, nullptr, DIM, 0, 0.f);

  finalize_loss<<<1, 1, 0, stream>>>(stats, out + (size_t)N_TOK * DIM);
}

// Round 3
// 418.524 us; speedup vs baseline: 2.2691x; 1.2666x over previous
//
#include <hip/hip_runtime.h>
#include <hip/hip_bf16.h>

typedef unsigned short u16;
typedef short bf16x8 __attribute__((ext_vector_type(8)));
typedef float f32x4 __attribute__((ext_vector_type(4)));

#define N_TOK 8192
#define DIM   1024
#define HID   2048
#define ADIM  128
#define SEQ   2048

__device__ __forceinline__ u16 f2bf_bits(float f){
  unsigned u = __float_as_uint(f);
  unsigned r = (u + 0x7fffu + ((u >> 16) & 1u)) >> 16;
  return (u16)r;
}
__device__ __forceinline__ float bf2f(u16 v){ return __uint_as_float((unsigned)v << 16); }
__device__ __forceinline__ float siluf(float x){ return x / (1.f + __expf(-x)); }

__device__ __forceinline__ void gload16(const void* g, void* l){
  __builtin_amdgcn_global_load_lds((const __attribute__((address_space(1))) void*)g,
                                   (__attribute__((address_space(3))) void*)l, 16, 0, 0);
}

// ---------------- generic C = A @ B^T GEMM, 128x128 tile, BK=32 -------------
enum { EPI_BF16 = 0, EPI_F32 = 1, EPI_SILU = 2, EPI_P1 = 3, EPI_OUTSCALE = 4,
       EPI_OUTADD = 5, EPI_HE = 6 };

template<int EPI>
__global__ void __launch_bounds__(256, 2)
gemm_bt(const u16* __restrict__ Ag, const u16* __restrict__ Bg, int K,
        long sAz, long sBz, long sOz, long sRz,
        float* __restrict__ fout, u16* __restrict__ bout,
        const float* __restrict__ rowscale, int ldo, int col0, float alpha)
{
  __shared__ u16 lA[128 * 32];
  __shared__ u16 lB[128 * 32];
  const int tid = threadIdx.x, wave = tid >> 6, lane = tid & 63;
  const long brow = (long)blockIdx.y * 128, bcol = (long)blockIdx.x * 128;
  const u16* A = Ag + (long)blockIdx.z * sAz + brow * K;
  const u16* B = Bg + (long)blockIdx.z * sBz + bcol * K;
  const int wr = (wave >> 1) * 64, wc = (wave & 1) * 64;

  f32x4 acc[4][4];
  #pragma unroll
  for (int m = 0; m < 4; m++)
    #pragma unroll
    for (int n = 0; n < 4; n++)
      #pragma unroll
      for (int i = 0; i < 4; i++) acc[m][n][i] = 0.f;

  const int sr = tid >> 2, sk = (tid & 3) * 8;
  const u16* gA = A + (long)sr * K + sk;
  const u16* gB = B + (long)sr * K + sk;
  const long rstep = (long)64 * K;
  u16* lA0 = &lA[wave * 512]; u16* lA1 = &lA[2048 + wave * 512];
  u16* lB0 = &lB[wave * 512]; u16* lB1 = &lB[2048 + wave * 512];
  const int frow = lane & 15, fk = (lane >> 4) * 8;

  for (int kt = 0; kt < K; kt += 32) {
    gload16(gA, lA0); gload16(gA + rstep, lA1);
    gload16(gB, lB0); gload16(gB + rstep, lB1);
    gA += 32; gB += 32;
    asm volatile("s_waitcnt vmcnt(0)" ::: "memory");
    __syncthreads();
    bf16x8 af[4], bfv[4];
    #pragma unroll
    for (int m = 0; m < 4; m++) af[m] = *(const bf16x8*)&lA[(wr + m * 16 + frow) * 32 + fk];
    #pragma unroll
    for (int n = 0; n < 4; n++) bfv[n] = *(const bf16x8*)&lB[(wc + n * 16 + frow) * 32 + fk];
    #pragma unroll
    for (int m = 0; m < 4; m++)
      #pragma unroll
      for (int n = 0; n < 4; n++)
        acc[m][n] = __builtin_amdgcn_mfma_f32_16x16x32_bf16(af[m], bfv[n], acc[m][n], 0, 0, 0);
    __syncthreads();
  }

  const long r0 = brow + wr + ((lane >> 4) << 2);
  const long c0 = bcol + wc + (lane & 15);
  #pragma unroll
  for (int m = 0; m < 4; m++) {
    #pragma unroll
    for (int i = 0; i < 4; i++) {
      long r = r0 + m * 16 + i;
      #pragma unroll
      for (int n = 0; n < 4; n++) {
        long c = c0 + n * 16;
        float v = acc[m][n][i];
        if constexpr (EPI == EPI_BF16) {
          bout[r * ldo + col0 + c] = f2bf_bits(v);
        } else if constexpr (EPI == EPI_F32) {
          fout[r * ldo + c] = v;
        } else if constexpr (EPI == EPI_SILU) {
          v = fminf(5.f, fmaxf(-5.f, v));
          (bout + (long)blockIdx.z * sOz)[r * ldo + c] = f2bf_bits(siluf(v));
        } else if constexpr (EPI == EPI_P1) {
          float rs = (rowscale + (long)blockIdx.z * sRz)[r];
          (bout + (long)blockIdx.z * sOz)[r * ldo + col0 + c] = f2bf_bits(alpha * rs * v);
        } else if constexpr (EPI == EPI_OUTSCALE) {
          fout[r * ldo + c] = rowscale[r] * v;
        } else if constexpr (EPI == EPI_OUTADD) {
          fout[r * ldo + c] += v;
        } else if constexpr (EPI == EPI_HE) {
          (bout + (long)blockIdx.z * sOz)[r * ldo + c] = f2bf_bits(v);
        }
      }
    }
  }
}

// -------- fused hidden = silu(x@Wg^T) * (x@Wu^T), 128x64 tile ---------------
__global__ void __launch_bounds__(256, 2)
gemm_dual(const u16* __restrict__ Ag, const u16* __restrict__ Gg,
          const u16* __restrict__ Ug, int K, int ldh, u16* __restrict__ hout)
{
  __shared__ u16 lA[128 * 32];
  __shared__ u16 lG[64 * 32];
  __shared__ u16 lU[64 * 32];
  const int tid = threadIdx.x, wave = tid >> 6, lane = tid & 63;
  const long brow = (long)blockIdx.y * 128, bcol = (long)blockIdx.x * 64;
  const u16* A = Ag + brow * K;
  const u16* G = Gg + bcol * K;
  const u16* U = Ug + bcol * K;
  const int wr = (wave >> 1) * 64, wc = (wave & 1) * 32;

  f32x4 ag[4][2], au[4][2];
  #pragma unroll
  for (int m = 0; m < 4; m++)
    #pragma unroll
    for (int n = 0; n < 2; n++)
      #pragma unroll
      for (int i = 0; i < 4; i++) { ag[m][n][i] = 0.f; au[m][n][i] = 0.f; }

  const int sr = tid >> 2, sk = (tid & 3) * 8;
  const u16* gA = A + (long)sr * K + sk;
  const u16* gG = G + (long)sr * K + sk;
  const u16* gU = U + (long)sr * K + sk;
  const long rstep = (long)64 * K;
  u16* lA0 = &lA[wave * 512]; u16* lA1 = &lA[2048 + wave * 512];
  u16* lG0 = &lG[wave * 512]; u16* lU0 = &lU[wave * 512];
  const int frow = lane & 15, fk = (lane >> 4) * 8;

  for (int kt = 0; kt < K; kt += 32) {
    gload16(gA, lA0); gload16(gA + rstep, lA1);
    gload16(gG, lG0); gload16(gU, lU0);
    gA += 32; gG += 32; gU += 32;
    asm volatile("s_waitcnt vmcnt(0)" ::: "memory");
    __syncthreads();
    bf16x8 af[4], bg[2], bu[2];
    #pragma unroll
    for (int m = 0; m < 4; m++) af[m] = *(const bf16x8*)&lA[(wr + m * 16 + frow) * 32 + fk];
    #pragma unroll
    for (int n = 0; n < 2; n++) bg[n] = *(const bf16x8*)&lG[(wc + n * 16 + frow) * 32 + fk];
    #pragma unroll
    for (int n = 0; n < 2; n++) bu[n] = *(const bf16x8*)&lU[(wc + n * 16 + frow) * 32 + fk];
    #pragma unroll
    for (int m = 0; m < 4; m++)
      #pragma unroll
      for (int n = 0; n < 2; n++) {
        ag[m][n] = __builtin_amdgcn_mfma_f32_16x16x32_bf16(af[m], bg[n], ag[m][n], 0, 0, 0);
        au[m][n] = __builtin_amdgcn_mfma_f32_16x16x32_bf16(af[m], bu[n], au[m][n], 0, 0, 0);
      }
    __syncthreads();
  }

  const long r0 = brow + wr + ((lane >> 4) << 2);
  const long c0 = bcol + wc + (lane & 15);
  #pragma unroll
  for (int m = 0; m < 4; m++)
    #pragma unroll
    for (int i = 0; i < 4; i++) {
      long r = r0 + m * 16 + i;
      #pragma unroll
      for (int n = 0; n < 2; n++) {
        long c = c0 + n * 16;
        hout[r * ldh + c] = f2bf_bits(siluf(ag[m][n][i]) * au[m][n][i]);
      }
    }
}

// ---------------- f32 -> bf16 conversions -----------------------------------
__global__ void cvt_bf16(const float* __restrict__ in, u16* __restrict__ out, int n)
{
  int i = (blockIdx.x * blockDim.x + threadIdx.x) * 8;
  if (i >= n) return;
  const float4* p = (const float4*)(in + i);
  float4 v0 = p[0], v1 = p[1];
  ushort4 a, b;
  a.x = f2bf_bits(v0.x); a.y = f2bf_bits(v0.y); a.z = f2bf_bits(v0.z); a.w = f2bf_bits(v0.w);
  b.x = f2bf_bits(v1.x); b.y = f2bf_bits(v1.y); b.z = f2bf_bits(v1.z); b.w = f2bf_bits(v1.w);
  *(ushort4*)(out + i) = a;
  *(ushort4*)(out + i + 4) = b;
}

// in [2048,128] -> out [128,2048] (bf16)
__global__ void cvt_t_bf16(const float* __restrict__ in, u16* __restrict__ out)
{
  int idx = blockIdx.x * 256 + threadIdx.x;      // 262144 total
  int c = idx >> 11, r = idx & 2047;
  out[idx] = f2bf_bits(in[(long)r * 128 + c]);
}

// ---------------- row LayerNorm over 128 cols -------------------------------
__global__ void __launch_bounds__(256)
ln_rows(const float* __restrict__ in, const float* __restrict__ g,
        const float* __restrict__ b, u16* __restrict__ out, u16* __restrict__ outT,
        u16* __restrict__ rawout)
{
  int wave = threadIdx.x >> 6, lane = threadIdx.x & 63;
  long n = (long)blockIdx.x * 4 + wave;
  const float* row = in + n * 128;
  float x0 = row[lane], x1 = row[lane + 64];
  float s = x0 + x1, q = x0 * x0 + x1 * x1;
  #pragma unroll
  for (int o = 32; o; o >>= 1) { s += __shfl_xor(s, o); q += __shfl_xor(q, o); }
  float m = s * (1.f / 128.f);
  float var = q * (1.f / 128.f) - m * m;
  float inv = rsqrtf(var + 1e-5f);
  float y0 = (x0 - m) * inv * g[lane] + b[lane];
  float y1 = (x1 - m) * inv * g[lane + 64] + b[lane + 64];
  out[n * 128 + lane] = f2bf_bits(y0);
  out[n * 128 + 64 + lane] = f2bf_bits(y1);
  if (outT) {
    long bb = n >> 11, ss = n & 2047;
    outT[(bb * 128 + lane) * 2048 + ss] = f2bf_bits(y0);
    outT[(bb * 128 + lane + 64) * 2048 + ss] = f2bf_bits(y1);
  }
  if (rawout) {
    rawout[n * 128 + lane] = f2bf_bits(x0);
    rawout[n * 128 + 64 + lane] = f2bf_bits(x1);
  }
}

// ---------------- router (fp32 exact, hierarchical stats reduction) ---------
// 512 blocks x 256 threads; wave handles 4 tokens; also emits x as bf16.
__global__ void __launch_bounds__(256)
router_kernel(const float* __restrict__ x, const float* __restrict__ Wrg,
              const float* __restrict__ Wre, float* __restrict__ sumw,
              float* __restrict__ fwv, int* __restrict__ eidxv,
              float* __restrict__ stats, u16* __restrict__ xb)
{
  __shared__ float lst[10];
  if (threadIdx.x < 10) lst[threadIdx.x] = 0.f;
  __syncthreads();
  const int wave = threadIdx.x >> 6, lane = threadIdx.x & 63;
  const float4* wg0 = (const float4*)Wrg;
  const float4* wg1 = (const float4*)(Wrg + 1024);
  const float4* we0 = (const float4*)Wre;
  const float4* we1 = (const float4*)(Wre + 1024);
  const float4* we2 = (const float4*)(Wre + 2048);
  const float4* we3 = (const float4*)(Wre + 3072);

  for (int t = 0; t < 4; t++) {
    const long n = (long)blockIdx.x * 16 + wave * 4 + t;
    const float4* xr = (const float4*)(x + n * 1024);
    float d0 = 0, d1 = 0, t0 = 0, t1 = 0, t2 = 0, t3 = 0;
    #pragma unroll
    for (int j = 0; j < 4; j++) {
      int id = j * 64 + lane;
      float4 xv = xr[id];
      ushort4 xc;
      xc.x = f2bf_bits(xv.x); xc.y = f2bf_bits(xv.y);
      xc.z = f2bf_bits(xv.z); xc.w = f2bf_bits(xv.w);
      *(ushort4*)(xb + n * 1024 + id * 4) = xc;
      float4 a;
      a = wg0[id]; d0 += xv.x * a.x + xv.y * a.y + xv.z * a.z + xv.w * a.w;
      a = wg1[id]; d1 += xv.x * a.x + xv.y * a.y + xv.z * a.z + xv.w * a.w;
      a = we0[id]; t0 += xv.x * a.x + xv.y * a.y + xv.z * a.z + xv.w * a.w;
      a = we1[id]; t1 += xv.x * a.x + xv.y * a.y + xv.z * a.z + xv.w * a.w;
      a = we2[id]; t2 += xv.x * a.x + xv.y * a.y + xv.z * a.z + xv.w * a.w;
      a = we3[id]; t3 += xv.x * a.x + xv.y * a.y + xv.z * a.z + xv.w * a.w;
    }
    #pragma unroll
    for (int o = 32; o; o >>= 1) {
      d0 += __shfl_xor(d0, o); d1 += __shfl_xor(d1, o);
      t0 += __shfl_xor(t0, o); t1 += __shfl_xor(t1, o);
      t2 += __shfl_xor(t2, o); t3 += __shfl_xor(t3, o);
    }
    if (lane == 0) {
      float mg = fmaxf(d0, d1);
      float e0 = __expf(d0 - mg), e1 = __expf(d1 - mg);
      float invg = 1.f / (e0 + e1);
      float p0 = e0 * invg, p1 = e1 * invg;
      int gi = (d1 > d0) ? 1 : 0;
      float gw = fmaxf(p0, p1);
      float l[4] = {t0, t1, t2, t3};
      float ml = fmaxf(fmaxf(l[0], l[1]), fmaxf(l[2], l[3]));
      float p[4]; float su = 0;
      #pragma unroll
      for (int i = 0; i < 4; i++) { p[i] = __expf(l[i] - ml); su += p[i]; }
      float isu = 1.f / su;
      #pragma unroll
      for (int i = 0; i < 4; i++) p[i] *= isu;
      int i1 = 0;
      #pragma unroll
      for (int i = 1; i < 4; i++) if (p[i] > p[i1]) i1 = i;
      int i2 = (i1 == 0) ? 1 : 0;
      #pragma unroll
      for (int i = 0; i < 4; i++) if (i != i1 && p[i] > p[i2]) i2 = i;
      float s2 = p[i1] + p[i2];
      float invs = 1.f / (s2 + 1e-7f);
      float f1 = gw * p[i1] * invs, f2 = gw * p[i2] * invs;
      int ea = gi * 4 + i1, eb = gi * 4 + i2;
      sumw[n] = f1 + f2;
      fwv[2 * n] = f1; fwv[2 * n + 1] = f2;
      eidxv[2 * n] = ea; eidxv[2 * n + 1] = eb;
      atomicAdd(&lst[ea], f1);
      atomicAdd(&lst[eb], f2);
      atomicAdd(&lst[8], d0 * d0 + d1 * d1);
      atomicAdd(&lst[9], t0 * t0 + t1 * t1 + t2 * t2 + t3 * t3);
    }
  }
  __syncthreads();
  if (threadIdx.x < 10) atomicAdd(&stats[threadIdx.x], lst[threadIdx.x]);
}

__global__ void init_stats(float* stats){ if (threadIdx.x < 16) stats[threadIdx.x] = 0.f; }

__global__ void finalize_loss(const float* __restrict__ stats, float* __restrict__ out)
{
  float tot = 0;
  #pragma unroll
  for (int e = 0; e < 8; e++) tot += stats[e];
  float target = tot * 0.125f;
  float lb = 0;
  #pragma unroll
  for (int e = 0; e < 8; e++) { float d = stats[e] - target; lb += d * d; }
  lb *= 0.125f;
  float z = stats[8] * (1.f / (8192.f * 2.f)) + stats[9] * (1.f / (8192.f * 4.f));
  out[0] = 0.001f * (lb + z);
}

// ------- LN + weighted combine of the 2 selected experts' he rows -----------
// he: [8, N, 128] bf16; one wave per token.
__global__ void __launch_bounds__(256)
ln_combine(const u16* __restrict__ he, const int* __restrict__ eidxv,
           const float* __restrict__ fwv, const float* __restrict__ g_e,
           const float* __restrict__ b_e, u16* __restrict__ P)
{
  const int wave = threadIdx.x >> 6, lane = threadIdx.x & 63;
  const long n = (long)blockIdx.x * 4 + wave;
  float o0 = 0.f, o1 = 0.f;
  #pragma unroll
  for (int k = 0; k < 2; k++) {
    const int e = eidxv[2 * n + k];
    const float w = fwv[2 * n + k];
    const u16* row = he + ((long)e * N_TOK + n) * 128;
    float h0 = bf2f(row[lane]), h1 = bf2f(row[lane + 64]);
    float s = h0 + h1, q = h0 * h0 + h1 * h1;
    #pragma unroll
    for (int o = 32; o; o >>= 1) { s += __shfl_xor(s, o); q += __shfl_xor(q, o); }
    float m = s * (1.f / 128.f);
    float var = q * (1.f / 128.f) - m * m;
    float inv = rsqrtf(var + 1e-5f);
    o0 += w * ((h0 - m) * inv * g_e[e * 128 + lane] + b_e[e * 128 + lane]);
    o1 += w * ((h1 - m) * inv * g_e[e * 128 + lane + 64] + b_e[e * 128 + lane + 64]);
  }
  P[n * 256 + 128 + lane] = f2bf_bits(0.1f * o0);
  P[n * 256 + 128 + 64 + lane] = f2bf_bits(0.1f * o1);
}

// ----------------------------------------------------------------------------
extern "C" void kernel_launch(void* const* d_in, const int* in_sizes, int n_in,
                              void* d_out, int out_size, void* d_ws, size_t ws_size,
                              hipStream_t stream)
{
  (void)in_sizes; (void)n_in; (void)out_size; (void)ws_size;
  const float* x       = (const float*)d_in[0];
  const float* W_up    = (const float*)d_in[1];
  const float* W_gate  = (const float*)d_in[2];
  const float* W_down  = (const float*)d_in[3];
  const float* W_pre   = (const float*)d_in[4];
  const float* W_post  = (const float*)d_in[5];
  const float* g_an    = (const float*)d_in[6];
  const float* b_an    = (const float*)d_in[7];
  const float* W_aproj = (const float*)d_in[8];
  const float* W_ead   = (const float*)d_in[9];
  const float* g_e     = (const float*)d_in[10];
  const float* b_e     = (const float*)d_in[11];
  const float* W_eproj = (const float*)d_in[12];
  const float* W_oproj = (const float*)d_in[13];
  const float* W_rg    = (const float*)d_in[14];
  const float* W_re    = (const float*)d_in[15];
  float* out = (float*)d_out;

  char* base = (char*)d_ws; size_t off = 0;
  auto alloc = [&](size_t bytes) -> void* {
    void* p = base + off; off = (off + bytes + 255) & ~(size_t)255; return p;
  };
  u16*   xb     = (u16*)  alloc((size_t)N_TOK * DIM * 2);
  u16*   Wupb   = (u16*)  alloc((size_t)HID * DIM * 2);
  u16*   Wgb    = (u16*)  alloc((size_t)HID * DIM * 2);
  u16*   Wdb    = (u16*)  alloc((size_t)DIM * HID * 2);
  u16*   Wpostb = (u16*)  alloc((size_t)ADIM * HID * 2);
  u16*   Wpreb  = (u16*)  alloc((size_t)ADIM * DIM * 2);
  u16*   WaTb   = (u16*)  alloc((size_t)ADIM * HID * 2);
  u16*   WeTb   = (u16*)  alloc((size_t)ADIM * HID * 2);
  u16*   Wob    = (u16*)  alloc((size_t)DIM * HID * 2);
  u16*   Qb     = (u16*)  alloc((size_t)DIM * 256 * 2);
  u16*   Weadb  = (u16*)  alloc((size_t)8 * ADIM * ADIM * 2);
  u16*   hid    = (u16*)  alloc((size_t)N_TOK * HID * 2);
  float* pre    = (float*)alloc((size_t)N_TOK * ADIM * 4);
  float* postf  = (float*)alloc((size_t)N_TOK * ADIM * 4);
  u16*   preb   = (u16*)  alloc((size_t)N_TOK * ADIM * 2);
  u16*   heb    = (u16*)  alloc((size_t)8 * N_TOK * ADIM * 2);
  u16*   a_in   = (u16*)  alloc((size_t)N_TOK * ADIM * 2);
  u16*   a_inT  = (u16*)  alloc((size_t)N_TOK * ADIM * 2);
  u16*   a_out  = (u16*)  alloc((size_t)N_TOK * ADIM * 2);
  u16*   Pb     = (u16*)  alloc((size_t)N_TOK * 256 * 2);
  float* sumw   = (float*)alloc((size_t)N_TOK * 4);
  float* fwv    = (float*)alloc((size_t)N_TOK * 2 * 4);
  int*   eidxv  = (int*)  alloc((size_t)N_TOK * 2 * 4);
  float* stats  = (float*)alloc(64);
  // aw (4 x 2048 x 2048 bf16, 33.5 MB) aliases d_out[0..8388607] — its lifetime
  // (scores GEMM -> adaptA GEMM) strictly precedes the down-GEMM's writes.
  u16* aw = (u16*)d_out;

  init_stats<<<1, 64, 0, stream>>>(stats);
  // router also produces xb (x as bf16)
  router_kernel<<<512, 256, 0, stream>>>(x, W_rg, W_re, sumw, fwv, eidxv, stats, xb);

  cvt_bf16<<<1024, 256, 0, stream>>>(W_up, Wupb, HID * DIM);
  cvt_bf16<<<1024, 256, 0, stream>>>(W_gate, Wgb, HID * DIM);
  cvt_bf16<<<1024, 256, 0, stream>>>(W_down, Wdb, DIM * HID);
  cvt_bf16<<<128, 256, 0, stream>>>(W_post, Wpostb, ADIM * HID);
  cvt_bf16<<<64, 256, 0, stream>>>(W_pre, Wpreb, ADIM * DIM);
  cvt_bf16<<<1024, 256, 0, stream>>>(W_oproj, Wob, DIM * HID);
  cvt_bf16<<<64, 256, 0, stream>>>(W_ead, Weadb, 8 * ADIM * ADIM);
  cvt_t_bf16<<<1024, 256, 0, stream>>>(W_aproj, WaTb);
  cvt_t_bf16<<<1024, 256, 0, stream>>>(W_eproj, WeTb);

  // M2 = W_down @ W_aproj -> Q[:,0:128];  M1 = W_oproj @ W_eproj -> Q[:,128:256]
  gemm_bt<EPI_BF16><<<dim3(1, 8, 1), 256, 0, stream>>>(Wdb, WaTb, HID, 0, 0, 0, 0,
      nullptr, Qb, nullptr, 256, 0, 0.f);
  gemm_bt<EPI_BF16><<<dim3(1, 8, 1), 256, 0, stream>>>(Wob, WeTb, HID, 0, 0, 0, 0,
      nullptr, Qb, nullptr, 256, 128, 0.f);

  // hidden = silu(x@Wg^T) * (x@Wu^T)   [N,H] bf16
  gemm_dual<<<dim3(32, 64, 1), 256, 0, stream>>>(xb, Wgb, Wupb, DIM, HID, hid);

  // pre = x @ W_pre^T  [N,128] f32 ; a_in = LN(pre) (+ transposed + raw bf16)
  gemm_bt<EPI_F32><<<dim3(1, 64, 1), 256, 0, stream>>>(xb, Wpreb, DIM, 0, 0, 0, 0,
      pre, nullptr, nullptr, ADIM, 0, 0.f);
  ln_rows<<<2048, 256, 0, stream>>>(pre, g_an, b_an, a_in, a_inT, preb);

  // he[e] = pre @ W_ead[e]^T  for all 8 experts (batched, bf16 out)
  gemm_bt<EPI_HE><<<dim3(1, 64, 8), 256, 0, stream>>>(preb, Weadb, ADIM,
      0, (long)ADIM * ADIM, (long)N_TOK * ADIM, 0,
      nullptr, heb, nullptr, ADIM, 0, 0.f);

  // P[:, 128:] = 0.1 * sum_k w_k * LN_e(he)   (gather 2 experts per token)
  ln_combine<<<2048, 256, 0, stream>>>(heb, eidxv, fwv, g_e, b_e, Pb);

  // postf = hidden @ W_post^T ; a_out = LN(postf)
  gemm_bt<EPI_F32><<<dim3(1, 64, 1), 256, 0, stream>>>(hid, Wpostb, HID, 0, 0, 0, 0,
      postf, nullptr, nullptr, ADIM, 0, 0.f);
  ln_rows<<<2048, 256, 0, stream>>>(postf, g_an, b_an, a_out, nullptr, nullptr);

  // aw[b] = silu(clip(a_in_b @ a_out_b^T))  (bf16, aliased onto d_out)
  gemm_bt<EPI_SILU><<<dim3(16, 16, 4), 256, 0, stream>>>(a_in, a_out, ADIM,
      (long)SEQ * ADIM, (long)SEQ * ADIM, (long)SEQ * SEQ, 0,
      nullptr, aw, nullptr, SEQ, 0, 0.f);

  // P[:, :128] = 0.1 * sumw * (aw_b @ a_in_b)   (K = SEQ)
  gemm_bt<EPI_P1><<<dim3(1, 16, 4), 256, 0, stream>>>(aw, a_inT, SEQ,
      (long)SEQ * SEQ, (long)ADIM * SEQ, (long)SEQ * 256, SEQ,
      nullptr, Pb, sumw, 256, 0, 0.1f);

  // out = sumw * (hidden @ W_down^T)
  gemm_bt<EPI_OUTSCALE><<<dim3(8, 64, 1), 256, 0, stream>>>(hid, Wdb, HID, 0, 0, 0, 0,
      out, nullptr, sumw, DIM, 0, 0.f);
  // out += P @ Q^T   (K = 256)
  gemm_bt<EPI_OUTADD><<<dim3(8, 64, 1), 256, 0, stream>>>(Pb, Qb, 256, 0, 0, 0, 0,
      out, nullptr, nullptr, DIM, 0, 0.f);

  finalize_loss<<<1, 1, 0, stream>>>(stats, out + (size_t)N_TOK * DIM);
}

// Round 4
// 346.707 us; speedup vs baseline: 2.7391x; 1.2071x over previous
//
#include <hip/hip_runtime.h>
#include <hip/hip_bf16.h>

typedef unsigned short u16;
typedef short bf16x8 __attribute__((ext_vector_type(8)));
typedef float f32x4 __attribute__((ext_vector_type(4)));

#define N_TOK 8192
#define DIM   1024
#define HID   2048
#define ADIM  128
#define SEQ   2048

__device__ __forceinline__ u16 f2bf_bits(float f){
  unsigned u = __float_as_uint(f);
  unsigned r = (u + 0x7fffu + ((u >> 16) & 1u)) >> 16;
  return (u16)r;
}
__device__ __forceinline__ float bf2f(u16 v){ return __uint_as_float((unsigned)v << 16); }
__device__ __forceinline__ float siluf(float x){ return x / (1.f + __expf(-x)); }

__device__ __forceinline__ void gload16(const void* g, void* l){
  __builtin_amdgcn_global_load_lds((const __attribute__((address_space(1))) void*)g,
                                   (__attribute__((address_space(3))) void*)l, 16, 0, 0);
}

// ---------------- generic C = A @ B^T GEMM, 128x128 tile, BK=32 -------------
enum { EPI_BF16 = 0, EPI_SILU = 2 };

template<int EPI>
__global__ void __launch_bounds__(256, 2)
gemm_bt(const u16* __restrict__ Ag, const u16* __restrict__ Bg, int K, int lda, int ldb,
        long sAz, long sBz, long sOz, u16* __restrict__ bout, int ldo, int col0)
{
  __shared__ u16 lA[128 * 32];
  __shared__ u16 lB[128 * 32];
  const int tid = threadIdx.x, wave = tid >> 6, lane = tid & 63;
  const long brow = (long)blockIdx.y * 128, bcol = (long)blockIdx.x * 128;
  const u16* A = Ag + (long)blockIdx.z * sAz + brow * lda;
  const u16* B = Bg + (long)blockIdx.z * sBz + bcol * ldb;
  const int wr = (wave >> 1) * 64, wc = (wave & 1) * 64;

  f32x4 acc[4][4];
  #pragma unroll
  for (int m = 0; m < 4; m++)
    #pragma unroll
    for (int n = 0; n < 4; n++)
      #pragma unroll
      for (int i = 0; i < 4; i++) acc[m][n][i] = 0.f;

  const int sr = tid >> 2, sk = (tid & 3) * 8;
  const u16* gA = A + (long)sr * lda + sk;
  const u16* gB = B + (long)sr * ldb + sk;
  const long rA = (long)64 * lda, rB = (long)64 * ldb;
  u16* lA0 = &lA[wave * 512]; u16* lA1 = &lA[2048 + wave * 512];
  u16* lB0 = &lB[wave * 512]; u16* lB1 = &lB[2048 + wave * 512];
  const int frow = lane & 15, fk = (lane >> 4) * 8;

  for (int kt = 0; kt < K; kt += 32) {
    gload16(gA, lA0); gload16(gA + rA, lA1);
    gload16(gB, lB0); gload16(gB + rB, lB1);
    gA += 32; gB += 32;
    asm volatile("s_waitcnt vmcnt(0)" ::: "memory");
    __syncthreads();
    bf16x8 af[4], bfv[4];
    #pragma unroll
    for (int m = 0; m < 4; m++) af[m] = *(const bf16x8*)&lA[(wr + m * 16 + frow) * 32 + fk];
    #pragma unroll
    for (int n = 0; n < 4; n++) bfv[n] = *(const bf16x8*)&lB[(wc + n * 16 + frow) * 32 + fk];
    #pragma unroll
    for (int m = 0; m < 4; m++)
      #pragma unroll
      for (int n = 0; n < 4; n++)
        acc[m][n] = __builtin_amdgcn_mfma_f32_16x16x32_bf16(af[m], bfv[n], acc[m][n], 0, 0, 0);
    __syncthreads();
  }

  const long r0 = brow + wr + ((lane >> 4) << 2);
  const long c0 = bcol + wc + (lane & 15);
  u16* O = bout + (long)blockIdx.z * sOz;
  #pragma unroll
  for (int m = 0; m < 4; m++) {
    #pragma unroll
    for (int i = 0; i < 4; i++) {
      long r = r0 + m * 16 + i;
      #pragma unroll
      for (int n = 0; n < 4; n++) {
        long c = c0 + n * 16;
        float v = acc[m][n][i];
        if constexpr (EPI == EPI_BF16) {
          O[r * ldo + col0 + c] = f2bf_bits(v);
        } else {
          v = fminf(5.f, fmaxf(-5.f, v));
          O[r * ldo + c] = f2bf_bits(siluf(v));
        }
      }
    }
  }
}

// ------------- split-K partial GEMM: 128 output cols, f32 partials ----------
// grid: (1, rows/128, nbatch*nsplit); part[((z*Mrows)+r)*128+c]
__global__ void __launch_bounds__(256, 2)
gemm_split(const u16* __restrict__ Ag, const u16* __restrict__ Bg, int Ksub, int nsplit,
           int lda, int ldb, long sAz, long sBz, float* __restrict__ part)
{
  __shared__ u16 lA[128 * 32];
  __shared__ u16 lB[128 * 32];
  const int tid = threadIdx.x, wave = tid >> 6, lane = tid & 63;
  const int z = blockIdx.z, batch = z / nsplit, split = z % nsplit;
  const long brow = (long)blockIdx.y * 128;
  const int Mrows = gridDim.y * 128;
  const u16* A = Ag + (long)batch * sAz + brow * lda + (long)split * Ksub;
  const u16* B = Bg + (long)batch * sBz + (long)split * Ksub;
  const int wr = (wave >> 1) * 64, wc = (wave & 1) * 64;

  f32x4 acc[4][4];
  #pragma unroll
  for (int m = 0; m < 4; m++)
    #pragma unroll
    for (int n = 0; n < 4; n++)
      #pragma unroll
      for (int i = 0; i < 4; i++) acc[m][n][i] = 0.f;

  const int sr = tid >> 2, sk = (tid & 3) * 8;
  const u16* gA = A + (long)sr * lda + sk;
  const u16* gB = B + (long)sr * ldb + sk;
  const long rA = (long)64 * lda, rB = (long)64 * ldb;
  u16* lA0 = &lA[wave * 512]; u16* lA1 = &lA[2048 + wave * 512];
  u16* lB0 = &lB[wave * 512]; u16* lB1 = &lB[2048 + wave * 512];
  const int frow = lane & 15, fk = (lane >> 4) * 8;

  for (int kt = 0; kt < Ksub; kt += 32) {
    gload16(gA, lA0); gload16(gA + rA, lA1);
    gload16(gB, lB0); gload16(gB + rB, lB1);
    gA += 32; gB += 32;
    asm volatile("s_waitcnt vmcnt(0)" ::: "memory");
    __syncthreads();
    bf16x8 af[4], bfv[4];
    #pragma unroll
    for (int m = 0; m < 4; m++) af[m] = *(const bf16x8*)&lA[(wr + m * 16 + frow) * 32 + fk];
    #pragma unroll
    for (int n = 0; n < 4; n++) bfv[n] = *(const bf16x8*)&lB[(wc + n * 16 + frow) * 32 + fk];
    #pragma unroll
    for (int m = 0; m < 4; m++)
      #pragma unroll
      for (int n = 0; n < 4; n++)
        acc[m][n] = __builtin_amdgcn_mfma_f32_16x16x32_bf16(af[m], bfv[n], acc[m][n], 0, 0, 0);
    __syncthreads();
  }

  float* po = part + (long)z * Mrows * 128;
  const long rr = brow + wr + ((lane >> 4) << 2);
  const int cc = wc + (lane & 15);
  #pragma unroll
  for (int m = 0; m < 4; m++)
    #pragma unroll
    for (int i = 0; i < 4; i++) {
      long r = rr + m * 16 + i;
      #pragma unroll
      for (int n = 0; n < 4; n++)
        po[r * 128 + cc + n * 16] = acc[m][n][i];
    }
}

// -------- fused hidden = silu(x@Wg^T) * (x@Wu^T), 128x64 tile ---------------
__global__ void __launch_bounds__(256, 2)
gemm_dual(const u16* __restrict__ Ag, const u16* __restrict__ Gg,
          const u16* __restrict__ Ug, int K, int ldh, u16* __restrict__ hout)
{
  __shared__ u16 lA[128 * 32];
  __shared__ u16 lG[64 * 32];
  __shared__ u16 lU[64 * 32];
  const int tid = threadIdx.x, wave = tid >> 6, lane = tid & 63;
  const long brow = (long)blockIdx.y * 128, bcol = (long)blockIdx.x * 64;
  const u16* A = Ag + brow * K;
  const u16* G = Gg + bcol * K;
  const u16* U = Ug + bcol * K;
  const int wr = (wave >> 1) * 64, wc = (wave & 1) * 32;

  f32x4 ag[4][2], au[4][2];
  #pragma unroll
  for (int m = 0; m < 4; m++)
    #pragma unroll
    for (int n = 0; n < 2; n++)
      #pragma unroll
      for (int i = 0; i < 4; i++) { ag[m][n][i] = 0.f; au[m][n][i] = 0.f; }

  const int sr = tid >> 2, sk = (tid & 3) * 8;
  const u16* gA = A + (long)sr * K + sk;
  const u16* gG = G + (long)sr * K + sk;
  const u16* gU = U + (long)sr * K + sk;
  const long rstep = (long)64 * K;
  u16* lA0 = &lA[wave * 512]; u16* lA1 = &lA[2048 + wave * 512];
  u16* lG0 = &lG[wave * 512]; u16* lU0 = &lU[wave * 512];
  const int frow = lane & 15, fk = (lane >> 4) * 8;

  for (int kt = 0; kt < K; kt += 32) {
    gload16(gA, lA0); gload16(gA + rstep, lA1);
    gload16(gG, lG0); gload16(gU, lU0);
    gA += 32; gG += 32; gU += 32;
    asm volatile("s_waitcnt vmcnt(0)" ::: "memory");
    __syncthreads();
    bf16x8 af[4], bg[2], bu[2];
    #pragma unroll
    for (int m = 0; m < 4; m++) af[m] = *(const bf16x8*)&lA[(wr + m * 16 + frow) * 32 + fk];
    #pragma unroll
    for (int n = 0; n < 2; n++) bg[n] = *(const bf16x8*)&lG[(wc + n * 16 + frow) * 32 + fk];
    #pragma unroll
    for (int n = 0; n < 2; n++) bu[n] = *(const bf16x8*)&lU[(wc + n * 16 + frow) * 32 + fk];
    #pragma unroll
    for (int m = 0; m < 4; m++)
      #pragma unroll
      for (int n = 0; n < 2; n++) {
        ag[m][n] = __builtin_amdgcn_mfma_f32_16x16x32_bf16(af[m], bg[n], ag[m][n], 0, 0, 0);
        au[m][n] = __builtin_amdgcn_mfma_f32_16x16x32_bf16(af[m], bu[n], au[m][n], 0, 0, 0);
      }
    __syncthreads();
  }

  const long r0 = brow + wr + ((lane >> 4) << 2);
  const long c0 = bcol + wc + (lane & 15);
  #pragma unroll
  for (int m = 0; m < 4; m++)
    #pragma unroll
    for (int i = 0; i < 4; i++) {
      long r = r0 + m * 16 + i;
      #pragma unroll
      for (int n = 0; n < 2; n++) {
        long c = c0 + n * 16;
        hout[r * ldh + c] = f2bf_bits(siluf(ag[m][n][i]) * au[m][n][i]);
      }
    }
}

// ---- fused out = sumw * (hid @ Wd^T) + P @ Q^T  (128x128 tile, f32 out) ----
__global__ void __launch_bounds__(256, 2)
gemm_out(const u16* __restrict__ hid, const u16* __restrict__ Wd,
         const u16* __restrict__ P, const u16* __restrict__ Q,
         const float* __restrict__ sumw, float* __restrict__ out)
{
  __shared__ u16 lA[128 * 32];
  __shared__ u16 lB[128 * 32];
  const int tid = threadIdx.x, wave = tid >> 6, lane = tid & 63;
  const long brow = (long)blockIdx.y * 128, bcol = (long)blockIdx.x * 128;
  const int wr = (wave >> 1) * 64, wc = (wave & 1) * 64;

  f32x4 acc[4][4];
  #pragma unroll
  for (int m = 0; m < 4; m++)
    #pragma unroll
    for (int n = 0; n < 4; n++)
      #pragma unroll
      for (int i = 0; i < 4; i++) acc[m][n][i] = 0.f;

  const int sr = tid >> 2, sk = (tid & 3) * 8;
  u16* lA0 = &lA[wave * 512]; u16* lA1 = &lA[2048 + wave * 512];
  u16* lB0 = &lB[wave * 512]; u16* lB1 = &lB[2048 + wave * 512];
  const int frow = lane & 15, fk = (lane >> 4) * 8;
  const long r0 = brow + wr + ((lane >> 4) << 2);
  const long c0 = bcol + wc + (lane & 15);

  // phase 1: K = 2048 over hid/Wd
  {
    const u16* gA = hid + brow * HID + (long)sr * HID + sk;
    const u16* gB = Wd + bcol * HID + (long)sr * HID + sk;
    const long rstep = (long)64 * HID;
    for (int kt = 0; kt < HID; kt += 32) {
      gload16(gA, lA0); gload16(gA + rstep, lA1);
      gload16(gB, lB0); gload16(gB + rstep, lB1);
      gA += 32; gB += 32;
      asm volatile("s_waitcnt vmcnt(0)" ::: "memory");
      __syncthreads();
      bf16x8 af[4], bfv[4];
      #pragma unroll
      for (int m = 0; m < 4; m++) af[m] = *(const bf16x8*)&lA[(wr + m * 16 + frow) * 32 + fk];
      #pragma unroll
      for (int n = 0; n < 4; n++) bfv[n] = *(const bf16x8*)&lB[(wc + n * 16 + frow) * 32 + fk];
      #pragma unroll
      for (int m = 0; m < 4; m++)
        #pragma unroll
        for (int n = 0; n < 4; n++)
          acc[m][n] = __builtin_amdgcn_mfma_f32_16x16x32_bf16(af[m], bfv[n], acc[m][n], 0, 0, 0);
      __syncthreads();
    }
  }
  // scale by per-row sumw
  #pragma unroll
  for (int m = 0; m < 4; m++)
    #pragma unroll
    for (int i = 0; i < 4; i++) {
      float rs = sumw[r0 + m * 16 + i];
      #pragma unroll
      for (int n = 0; n < 4; n++) acc[m][n][i] *= rs;
    }
  // phase 2: K = 256 over P/Q, accumulate on top
  {
    const u16* gA = P + brow * 256 + (long)sr * 256 + sk;
    const u16* gB = Q + bcol * 256 + (long)sr * 256 + sk;
    const long rstep = (long)64 * 256;
    for (int kt = 0; kt < 256; kt += 32) {
      gload16(gA, lA0); gload16(gA + rstep, lA1);
      gload16(gB, lB0); gload16(gB + rstep, lB1);
      gA += 32; gB += 32;
      asm volatile("s_waitcnt vmcnt(0)" ::: "memory");
      __syncthreads();
      bf16x8 af[4], bfv[4];
      #pragma unroll
      for (int m = 0; m < 4; m++) af[m] = *(const bf16x8*)&lA[(wr + m * 16 + frow) * 32 + fk];
      #pragma unroll
      for (int n = 0; n < 4; n++) bfv[n] = *(const bf16x8*)&lB[(wc + n * 16 + frow) * 32 + fk];
      #pragma unroll
      for (int m = 0; m < 4; m++)
        #pragma unroll
        for (int n = 0; n < 4; n++)
          acc[m][n] = __builtin_amdgcn_mfma_f32_16x16x32_bf16(af[m], bfv[n], acc[m][n], 0, 0, 0);
      __syncthreads();
    }
  }
  #pragma unroll
  for (int m = 0; m < 4; m++)
    #pragma unroll
    for (int i = 0; i < 4; i++) {
      long r = r0 + m * 16 + i;
      #pragma unroll
      for (int n = 0; n < 4; n++)
        out[r * DIM + c0 + n * 16] = acc[m][n][i];
    }
}

// ---------------- merged f32 -> bf16 conversions ----------------------------
__global__ void cvt_all(const float* __restrict__ a0, const float* __restrict__ a1,
                        const float* __restrict__ a2, const float* __restrict__ a3,
                        const float* __restrict__ a4, const float* __restrict__ a5,
                        const float* __restrict__ a6,
                        u16* __restrict__ b0, u16* __restrict__ b1, u16* __restrict__ b2,
                        u16* __restrict__ b3, u16* __restrict__ b4, u16* __restrict__ b5,
                        u16* __restrict__ b6)
{
  long i = ((long)blockIdx.x * 256 + threadIdx.x) * 8;
  const float* s; u16* d; long j;
  if      (i < 2097152) { s = a0; d = b0; j = i; }
  else if (i < 4194304) { s = a1; d = b1; j = i - 2097152; }
  else if (i < 6291456) { s = a2; d = b2; j = i - 4194304; }
  else if (i < 8388608) { s = a3; d = b3; j = i - 6291456; }
  else if (i < 8650752) { s = a4; d = b4; j = i - 8388608; }
  else if (i < 8781824) { s = a5; d = b5; j = i - 8650752; }
  else                  { s = a6; d = b6; j = i - 8781824; }
  float4 v0 = *(const float4*)(s + j), v1 = *(const float4*)(s + j + 4);
  ushort4 p, q;
  p.x = f2bf_bits(v0.x); p.y = f2bf_bits(v0.y); p.z = f2bf_bits(v0.z); p.w = f2bf_bits(v0.w);
  q.x = f2bf_bits(v1.x); q.y = f2bf_bits(v1.y); q.z = f2bf_bits(v1.z); q.w = f2bf_bits(v1.w);
  *(ushort4*)(d + j) = p;
  *(ushort4*)(d + j + 4) = q;
}

// both [2048,128] -> [128,2048] transposes in one launch
__global__ void cvt_t2(const float* __restrict__ Wa, const float* __restrict__ We,
                       u16* __restrict__ Ta, u16* __restrict__ Te)
{
  int bid = blockIdx.x;
  const float* src = (bid < 1024) ? Wa : We;
  u16* dst = (bid < 1024) ? Ta : Te;
  int idx = (bid & 1023) * 256 + threadIdx.x;
  int c = idx >> 11, r = idx & 2047;
  dst[idx] = f2bf_bits(src[(long)r * 128 + c]);
}

// ------- row LayerNorm over 128 cols, input = sum of nsplit f32 partials ----
__global__ void __launch_bounds__(256)
ln_rows_part(const float* __restrict__ part, int nsplit,
             const float* __restrict__ g, const float* __restrict__ b,
             u16* __restrict__ out, u16* __restrict__ outT, u16* __restrict__ rawout)
{
  int wave = threadIdx.x >> 6, lane = threadIdx.x & 63;
  long n = (long)blockIdx.x * 4 + wave;
  long base = n * 128;
  float x0 = 0.f, x1 = 0.f;
  for (int s = 0; s < nsplit; s++) {
    x0 += part[(long)s * (N_TOK * ADIM) + base + lane];
    x1 += part[(long)s * (N_TOK * ADIM) + base + 64 + lane];
  }
  float s2 = x0 + x1, q = x0 * x0 + x1 * x1;
  #pragma unroll
  for (int o = 32; o; o >>= 1) { s2 += __shfl_xor(s2, o); q += __shfl_xor(q, o); }
  float m = s2 * (1.f / 128.f);
  float var = q * (1.f / 128.f) - m * m;
  float inv = rsqrtf(var + 1e-5f);
  float y0 = (x0 - m) * inv * g[lane] + b[lane];
  float y1 = (x1 - m) * inv * g[lane + 64] + b[lane + 64];
  out[base + lane] = f2bf_bits(y0);
  out[base + 64 + lane] = f2bf_bits(y1);
  if (outT) {
    long bb = n >> 11, ss = n & 2047;
    outT[(bb * 128 + lane) * 2048 + ss] = f2bf_bits(y0);
    outT[(bb * 128 + lane + 64) * 2048 + ss] = f2bf_bits(y1);
  }
  if (rawout) {
    rawout[base + lane] = f2bf_bits(x0);
    rawout[base + 64 + lane] = f2bf_bits(x1);
  }
}

// ------- P1 reduce: P[:, :128] = 0.1*sumw[n]*sum_s part -------------------
__global__ void reduce_part_p1(const float* __restrict__ part,
                               const float* __restrict__ sumw, u16* __restrict__ P)
{
  int idx = blockIdx.x * 256 + threadIdx.x;   // 262144 = 8192 * 32
  int n = idx >> 5, c4 = (idx & 31) * 4;
  int batch = n >> 11, r = n & 2047;
  float4 a = {0.f, 0.f, 0.f, 0.f};
  #pragma unroll
  for (int s = 0; s < 4; s++) {
    float4 v = *(const float4*)(part + (((long)(batch * 4 + s) * 2048 + r) << 7) + c4);
    a.x += v.x; a.y += v.y; a.z += v.z; a.w += v.w;
  }
  float rs = 0.1f * sumw[n];
  ushort4 o;
  o.x = f2bf_bits(rs * a.x); o.y = f2bf_bits(rs * a.y);
  o.z = f2bf_bits(rs * a.z); o.w = f2bf_bits(rs * a.w);
  *(ushort4*)(P + (long)n * 256 + c4) = o;
}

// ---------------- router (fp32 exact, hierarchical stats reduction) ---------
__global__ void __launch_bounds__(256)
router_kernel(const float* __restrict__ x, const float* __restrict__ Wrg,
              const float* __restrict__ Wre, float* __restrict__ sumw,
              float* __restrict__ fwv, int* __restrict__ eidxv,
              float* __restrict__ stats, u16* __restrict__ xb)
{
  __shared__ float lst[10];
  if (threadIdx.x < 10) lst[threadIdx.x] = 0.f;
  __syncthreads();
  const int wave = threadIdx.x >> 6, lane = threadIdx.x & 63;
  const float4* wg0 = (const float4*)Wrg;
  const float4* wg1 = (const float4*)(Wrg + 1024);
  const float4* we0 = (const float4*)Wre;
  const float4* we1 = (const float4*)(Wre + 1024);
  const float4* we2 = (const float4*)(Wre + 2048);
  const float4* we3 = (const float4*)(Wre + 3072);

  for (int t = 0; t < 4; t++) {
    const long n = (long)blockIdx.x * 16 + wave * 4 + t;
    const float4* xr = (const float4*)(x + n * 1024);
    float d0 = 0, d1 = 0, t0 = 0, t1 = 0, t2 = 0, t3 = 0;
    #pragma unroll
    for (int j = 0; j < 4; j++) {
      int id = j * 64 + lane;
      float4 xv = xr[id];
      ushort4 xc;
      xc.x = f2bf_bits(xv.x); xc.y = f2bf_bits(xv.y);
      xc.z = f2bf_bits(xv.z); xc.w = f2bf_bits(xv.w);
      *(ushort4*)(xb + n * 1024 + id * 4) = xc;
      float4 a;
      a = wg0[id]; d0 += xv.x * a.x + xv.y * a.y + xv.z * a.z + xv.w * a.w;
      a = wg1[id]; d1 += xv.x * a.x + xv.y * a.y + xv.z * a.z + xv.w * a.w;
      a = we0[id]; t0 += xv.x * a.x + xv.y * a.y + xv.z * a.z + xv.w * a.w;
      a = we1[id]; t1 += xv.x * a.x + xv.y * a.y + xv.z * a.z + xv.w * a.w;
      a = we2[id]; t2 += xv.x * a.x + xv.y * a.y + xv.z * a.z + xv.w * a.w;
      a = we3[id]; t3 += xv.x * a.x + xv.y * a.y + xv.z * a.z + xv.w * a.w;
    }
    #pragma unroll
    for (int o = 32; o; o >>= 1) {
      d0 += __shfl_xor(d0, o); d1 += __shfl_xor(d1, o);
      t0 += __shfl_xor(t0, o); t1 += __shfl_xor(t1, o);
      t2 += __shfl_xor(t2, o); t3 += __shfl_xor(t3, o);
    }
    if (lane == 0) {
      float mg = fmaxf(d0, d1);
      float e0 = __expf(d0 - mg), e1 = __expf(d1 - mg);
      float invg = 1.f / (e0 + e1);
      float p0 = e0 * invg, p1 = e1 * invg;
      int gi = (d1 > d0) ? 1 : 0;
      float gw = fmaxf(p0, p1);
      float l[4] = {t0, t1, t2, t3};
      float ml = fmaxf(fmaxf(l[0], l[1]), fmaxf(l[2], l[3]));
      float p[4]; float su = 0;
      #pragma unroll
      for (int i = 0; i < 4; i++) { p[i] = __expf(l[i] - ml); su += p[i]; }
      float isu = 1.f / su;
      #pragma unroll
      for (int i = 0; i < 4; i++) p[i] *= isu;
      int i1 = 0;
      #pragma unroll
      for (int i = 1; i < 4; i++) if (p[i] > p[i1]) i1 = i;
      int i2 = (i1 == 0) ? 1 : 0;
      #pragma unroll
      for (int i = 0; i < 4; i++) if (i != i1 && p[i] > p[i2]) i2 = i;
      float s2 = p[i1] + p[i2];
      float invs = 1.f / (s2 + 1e-7f);
      float f1 = gw * p[i1] * invs, f2 = gw * p[i2] * invs;
      int ea = gi * 4 + i1, eb = gi * 4 + i2;
      sumw[n] = f1 + f2;
      fwv[2 * n] = f1; fwv[2 * n + 1] = f2;
      eidxv[2 * n] = ea; eidxv[2 * n + 1] = eb;
      atomicAdd(&lst[ea], f1);
      atomicAdd(&lst[eb], f2);
      atomicAdd(&lst[8], d0 * d0 + d1 * d1);
      atomicAdd(&lst[9], t0 * t0 + t1 * t1 + t2 * t2 + t3 * t3);
    }
  }
  __syncthreads();
  if (threadIdx.x < 10) atomicAdd(&stats[threadIdx.x], lst[threadIdx.x]);
}

__global__ void init_stats(float* stats){ if (threadIdx.x < 16) stats[threadIdx.x] = 0.f; }

__global__ void finalize_loss(const float* __restrict__ stats, float* __restrict__ out)
{
  float tot = 0;
  #pragma unroll
  for (int e = 0; e < 8; e++) tot += stats[e];
  float target = tot * 0.125f;
  float lb = 0;
  #pragma unroll
  for (int e = 0; e < 8; e++) { float d = stats[e] - target; lb += d * d; }
  lb *= 0.125f;
  float z = stats[8] * (1.f / (8192.f * 2.f)) + stats[9] * (1.f / (8192.f * 4.f));
  out[0] = 0.001f * (lb + z);
}

// ------- LN + weighted combine of the 2 selected experts' he rows -----------
__global__ void __launch_bounds__(256)
ln_combine(const u16* __restrict__ he, const int* __restrict__ eidxv,
           const float* __restrict__ fwv, const float* __restrict__ g_e,
           const float* __restrict__ b_e, u16* __restrict__ P)
{
  const int wave = threadIdx.x >> 6, lane = threadIdx.x & 63;
  const long n = (long)blockIdx.x * 4 + wave;
  float o0 = 0.f, o1 = 0.f;
  #pragma unroll
  for (int k = 0; k < 2; k++) {
    const int e = eidxv[2 * n + k];
    const float w = fwv[2 * n + k];
    const u16* row = he + ((long)e * N_TOK + n) * 128;
    float h0 = bf2f(row[lane]), h1 = bf2f(row[lane + 64]);
    float s = h0 + h1, q = h0 * h0 + h1 * h1;
    #pragma unroll
    for (int o = 32; o; o >>= 1) { s += __shfl_xor(s, o); q += __shfl_xor(q, o); }
    float m = s * (1.f / 128.f);
    float var = q * (1.f / 128.f) - m * m;
    float inv = rsqrtf(var + 1e-5f);
    o0 += w * ((h0 - m) * inv * g_e[e * 128 + lane] + b_e[e * 128 + lane]);
    o1 += w * ((h1 - m) * inv * g_e[e * 128 + lane + 64] + b_e[e * 128 + lane + 64]);
  }
  P[n * 256 + 128 + lane] = f2bf_bits(0.1f * o0);
  P[n * 256 + 128 + 64 + lane] = f2bf_bits(0.1f * o1);
}

// ----------------------------------------------------------------------------
extern "C" void kernel_launch(void* const* d_in, const int* in_sizes, int n_in,
                              void* d_out, int out_size, void* d_ws, size_t ws_size,
                              hipStream_t stream)
{
  (void)in_sizes; (void)n_in; (void)out_size; (void)ws_size;
  const float* x       = (const float*)d_in[0];
  const float* W_up    = (const float*)d_in[1];
  const float* W_gate  = (const float*)d_in[2];
  const float* W_down  = (const float*)d_in[3];
  const float* W_pre   = (const float*)d_in[4];
  const float* W_post  = (const float*)d_in[5];
  const float* g_an    = (const float*)d_in[6];
  const float* b_an    = (const float*)d_in[7];
  const float* W_aproj = (const float*)d_in[8];
  const float* W_ead   = (const float*)d_in[9];
  const float* g_e     = (const float*)d_in[10];
  const float* b_e     = (const float*)d_in[11];
  const float* W_eproj = (const float*)d_in[12];
  const float* W_oproj = (const float*)d_in[13];
  const float* W_rg    = (const float*)d_in[14];
  const float* W_re    = (const float*)d_in[15];
  float* out = (float*)d_out;

  char* base = (char*)d_ws; size_t off = 0;
  auto alloc = [&](size_t bytes) -> void* {
    void* p = base + off; off = (off + bytes + 255) & ~(size_t)255; return p;
  };
  u16*   xb     = (u16*)  alloc((size_t)N_TOK * DIM * 2);
  u16*   Wupb   = (u16*)  alloc((size_t)HID * DIM * 2);
  u16*   Wgb    = (u16*)  alloc((size_t)HID * DIM * 2);
  u16*   Wdb    = (u16*)  alloc((size_t)DIM * HID * 2);
  u16*   Wpostb = (u16*)  alloc((size_t)ADIM * HID * 2);
  u16*   Wpreb  = (u16*)  alloc((size_t)ADIM * DIM * 2);
  u16*   WaTb   = (u16*)  alloc((size_t)ADIM * HID * 2);
  u16*   WeTb   = (u16*)  alloc((size_t)ADIM * HID * 2);
  u16*   Wob    = (u16*)  alloc((size_t)DIM * HID * 2);
  u16*   Qb     = (u16*)  alloc((size_t)DIM * 256 * 2);
  u16*   Weadb  = (u16*)  alloc((size_t)8 * ADIM * ADIM * 2);
  u16*   hid    = (u16*)  alloc((size_t)N_TOK * HID * 2);
  // part arena (16.78 MB) is time-shared: pre-partials -> heb -> postf-partials
  // -> P1-partials; every use strictly precedes the next writer.
  u16*   heb    = (u16*)  alloc((size_t)8 * N_TOK * ADIM * 2);
  float* part   = (float*)heb;
  u16*   preb   = (u16*)  alloc((size_t)N_TOK * ADIM * 2);
  u16*   a_in   = (u16*)  alloc((size_t)N_TOK * ADIM * 2);
  u16*   a_inT  = (u16*)  alloc((size_t)N_TOK * ADIM * 2);
  u16*   a_out  = (u16*)  alloc((size_t)N_TOK * ADIM * 2);
  u16*   Pb     = (u16*)  alloc((size_t)N_TOK * 256 * 2);
  float* sumw   = (float*)alloc((size_t)N_TOK * 4);
  float* fwv    = (float*)alloc((size_t)N_TOK * 2 * 4);
  int*   eidxv  = (int*)  alloc((size_t)N_TOK * 2 * 4);
  float* stats  = (float*)alloc(64);
  // aw (4 x 2048 x 2048 bf16, 33.5 MB) aliases d_out — lifetime (SILU GEMM ->
  // P1 split GEMM) strictly precedes gemm_out's writes.
  u16* aw = (u16*)d_out;

  init_stats<<<1, 64, 0, stream>>>(stats);
  router_kernel<<<512, 256, 0, stream>>>(x, W_rg, W_re, sumw, fwv, eidxv, stats, xb);

  cvt_all<<<4352, 256, 0, stream>>>(W_up, W_gate, W_down, W_oproj, W_post, W_pre, W_ead,
                                    Wupb, Wgb, Wdb, Wob, Wpostb, Wpreb, Weadb);
  cvt_t2<<<2048, 256, 0, stream>>>(W_aproj, W_eproj, WaTb, WeTb);

  // M2 = W_down @ W_aproj -> Q[:,0:128];  M1 = W_oproj @ W_eproj -> Q[:,128:256]
  gemm_bt<EPI_BF16><<<dim3(1, 8, 1), 256, 0, stream>>>(Wdb, WaTb, HID, HID, HID,
      0, 0, 0, Qb, 256, 0);
  gemm_bt<EPI_BF16><<<dim3(1, 8, 1), 256, 0, stream>>>(Wob, WeTb, HID, HID, HID,
      0, 0, 0, Qb, 256, 128);

  // hidden = silu(x@Wg^T) * (x@Wu^T)   [N,H] bf16
  gemm_dual<<<dim3(32, 64, 1), 256, 0, stream>>>(xb, Wgb, Wupb, DIM, HID, hid);

  // pre = x @ W_pre^T : split-K (4 x 256), partials then fused LN
  gemm_split<<<dim3(1, 64, 4), 256, 0, stream>>>(xb, Wpreb, 256, 4, DIM, DIM, 0, 0, part);
  ln_rows_part<<<2048, 256, 0, stream>>>(part, 4, g_an, b_an, a_in, a_inT, preb);

  // he[e] = pre @ W_ead[e]^T for all 8 experts (overwrites part arena)
  gemm_bt<EPI_BF16><<<dim3(1, 64, 8), 256, 0, stream>>>(preb, Weadb, ADIM, ADIM, ADIM,
      0, (long)ADIM * ADIM, (long)N_TOK * ADIM, heb, ADIM, 0);
  ln_combine<<<2048, 256, 0, stream>>>(heb, eidxv, fwv, g_e, b_e, Pb);

  // postf = hidden @ W_post^T : split-K (4 x 512) -> fused LN
  gemm_split<<<dim3(1, 64, 4), 256, 0, stream>>>(hid, Wpostb, 512, 4, HID, HID, 0, 0, part);
  ln_rows_part<<<2048, 256, 0, stream>>>(part, 4, g_an, b_an, a_out, nullptr, nullptr);

  // aw[b] = silu(clip(a_in_b @ a_out_b^T))  (bf16, aliased onto d_out)
  gemm_bt<EPI_SILU><<<dim3(16, 16, 4), 256, 0, stream>>>(a_in, a_out, ADIM, ADIM, ADIM,
      (long)SEQ * ADIM, (long)SEQ * ADIM, (long)SEQ * SEQ, aw, SEQ, 0);

  // P1 partials: aw_b @ a_inT_b^T, split-K (4 x 512), 4 batches
  gemm_split<<<dim3(1, 16, 16), 256, 0, stream>>>(aw, a_inT, 512, 4, SEQ, SEQ,
      (long)SEQ * SEQ, (long)ADIM * SEQ, part);
  reduce_part_p1<<<1024, 256, 0, stream>>>(part, sumw, Pb);

  // out = sumw * (hidden @ W_down^T) + P @ Q^T   (fused)
  gemm_out<<<dim3(8, 64, 1), 256, 0, stream>>>(hid, Wdb, Pb, Qb, sumw, out);

  finalize_loss<<<1, 1, 0, stream>>>(stats, out + (size_t)N_TOK * DIM);
}